// Round 1
// baseline (1145.084 us; speedup 1.0000x reference)
//
#include <hip/hip_runtime.h>
#include <hip/hip_bf16.h>
#include <cstdint>
#include <cstddef>

typedef __bf16 bf16;
typedef __attribute__((ext_vector_type(8))) __bf16 bf16x8;
typedef __attribute__((ext_vector_type(4))) float f32x4;

static constexpr int Dm = 2048;   // model dim
static constexpr int Sq = 2048;   // seq len
static constexpr int Hn = 16;     // heads
static constexpr int HDn = 128;   // head dim
static constexpr int MR = 4096;   // B*S rows

// ---------------- async global->LDS (16B per lane) ----------------
__device__ __forceinline__ void gload_lds16(const void* gp, void* lp) {
  __builtin_amdgcn_global_load_lds(
      (__attribute__((address_space(1))) void*)(void*)gp,
      (__attribute__((address_space(3))) void*)lp,
      16, 0, 0);
}

// ---------------- LayerNorm: fp32 in -> bf16 out ----------------
__global__ __launch_bounds__(256) void ln_kernel(const float* __restrict__ x,
                                                 const float* __restrict__ g,
                                                 const float* __restrict__ be,
                                                 bf16* __restrict__ out) {
  const int row = blockIdx.x;
  const int t = threadIdx.x;
  const float* xr = x + (size_t)row * Dm;
  f32x4 a = *(const f32x4*)(xr + t * 8);
  f32x4 b = *(const f32x4*)(xr + t * 8 + 4);
  float s = 0.f, ss = 0.f;
#pragma unroll
  for (int i = 0; i < 4; i++) { s += a[i] + b[i]; ss += a[i]*a[i] + b[i]*b[i]; }
#pragma unroll
  for (int off = 32; off > 0; off >>= 1) { s += __shfl_xor(s, off); ss += __shfl_xor(ss, off); }
  __shared__ float ls[4], lss[4];
  if ((t & 63) == 0) { ls[t >> 6] = s; lss[t >> 6] = ss; }
  __syncthreads();
  s = ls[0] + ls[1] + ls[2] + ls[3];
  ss = lss[0] + lss[1] + lss[2] + lss[3];
  const float mean = s * (1.f / Dm);
  const float rstd = rsqrtf(ss * (1.f / Dm) - mean * mean + 1e-5f);
  f32x4 g0 = *(const f32x4*)(g + t * 8);
  f32x4 g1 = *(const f32x4*)(g + t * 8 + 4);
  f32x4 b0 = *(const f32x4*)(be + t * 8);
  f32x4 b1 = *(const f32x4*)(be + t * 8 + 4);
  bf16x8 o;
#pragma unroll
  for (int i = 0; i < 4; i++) {
    o[i]     = (bf16)((a[i] - mean) * rstd * g0[i] + b0[i]);
    o[i + 4] = (bf16)((b[i] - mean) * rstd * g1[i] + b1[i]);
  }
  *(bf16x8*)(out + (size_t)row * Dm + t * 8) = o;
}

// ------------- transpose + fp32->bf16 convert: out[c][r] = in[r][c] -------------
__global__ void cvtT_kernel(const float* __restrict__ in, bf16* __restrict__ out,
                            int R, int C) {
  __shared__ float tile[32][33];
  const int c0 = blockIdx.x * 32, r0 = blockIdx.y * 32;
  const int tx = threadIdx.x, ty = threadIdx.y;
#pragma unroll
  for (int i = 0; i < 4; i++)
    tile[ty + i * 8][tx] = in[(size_t)(r0 + ty + i * 8) * C + c0 + tx];
  __syncthreads();
#pragma unroll
  for (int i = 0; i < 4; i++)
    out[(size_t)(c0 + ty + i * 8) * R + r0 + tx] = (bf16)tile[tx][ty + i * 8];
}

// ------------- extract V^T per (b,h): vt[bh][d][s] = qkv[b*S+s][2D + h*HD + d] -------------
__global__ void vtx_kernel(const bf16* __restrict__ qkv, bf16* __restrict__ vt) {
  __shared__ bf16 tile[32][33];
  const int s0 = blockIdx.x * 32;
  const int d0 = blockIdx.y * 32;
  const int bh = blockIdx.z;
  const int b = bh >> 4, h = bh & 15;
  const int tx = threadIdx.x, ty = threadIdx.y;
#pragma unroll
  for (int i = 0; i < 4; i++)
    tile[ty + i * 8][tx] =
        qkv[(size_t)(b * Sq + s0 + ty + i * 8) * (3 * Dm) + 2 * Dm + h * HDn + d0 + tx];
  __syncthreads();
#pragma unroll
  for (int i = 0; i < 4; i++)
    vt[((size_t)bh * HDn + d0 + ty + i * 8) * Sq + s0 + tx] = tile[tx][ty + i * 8];
}

// ---------------- GEMM: C[M,N] = A[M,K](bf16) @ BT[N,K](bf16), fused epilogues ----------------
// EPI 0: store bf16
// EPI 1: + resid(fp32), store fp32
// EPI 2: + bias, exact GELU, store bf16
// EPI 3: + bias + resid, store fp32
template <int EPI>
__global__ __launch_bounds__(256) void gemm_bt(const bf16* __restrict__ A,
                                               const bf16* __restrict__ BT,
                                               void* __restrict__ Cout,
                                               const float* __restrict__ bias,
                                               const float* __restrict__ resid,
                                               int M, int N, int K) {
  __shared__ alignas(16) bf16 As[128 * 32];
  __shared__ alignas(16) bf16 Bs[128 * 32];
  const int t = threadIdx.x;
  const int l = t & 63;
  const int wv = t >> 6, wr = wv >> 1, wc = wv & 1;
  const int lr = l & 15, lk = l >> 4;
  const int m0 = blockIdx.x * 128, n0 = blockIdx.y * 128;
  f32x4 acc[4][4] = {};

  const int ar = t >> 2;            // staging row within tile (0..63)
  const int ak = (t & 3) << 3;      // staging k offset (bf16 elems)
  const bf16* Ag  = A  + (size_t)(m0 + ar) * K + ak;
  const bf16* Ag2 = Ag + (size_t)64 * K;
  const bf16* Bg  = BT + (size_t)(n0 + ar) * K + ak;
  const bf16* Bg2 = Bg + (size_t)64 * K;
  bf16* Asd  = As + t * 8;
  bf16* Asd2 = As + 2048 + t * 8;
  bf16* Bsd  = Bs + t * 8;
  bf16* Bsd2 = Bs + 2048 + t * 8;

  const int nk = K >> 5;
  for (int kt = 0; kt < nk; ++kt) {
    gload_lds16(Ag, Asd);
    gload_lds16(Ag2, Asd2);
    gload_lds16(Bg, Bsd);
    gload_lds16(Bg2, Bsd2);
    Ag += 32; Ag2 += 32; Bg += 32; Bg2 += 32;
    __syncthreads();
    bf16x8 af[4], bfr[4];
#pragma unroll
    for (int m = 0; m < 4; ++m)
      af[m] = *(const bf16x8*)(As + (wr * 64 + m * 16 + lr) * 32 + lk * 8);
#pragma unroll
    for (int n = 0; n < 4; ++n)
      bfr[n] = *(const bf16x8*)(Bs + (wc * 64 + n * 16 + lr) * 32 + lk * 8);
#pragma unroll
    for (int m = 0; m < 4; ++m)
#pragma unroll
      for (int n = 0; n < 4; ++n)
        acc[m][n] = __builtin_amdgcn_mfma_f32_16x16x32_bf16(af[m], bfr[n], acc[m][n], 0, 0, 0);
    __syncthreads();
  }

  const int rb = m0 + wr * 64 + lk * 4;  // + m*16 + j
  const int cb = n0 + wc * 64 + lr;      // + n*16
#pragma unroll
  for (int m = 0; m < 4; ++m) {
#pragma unroll
    for (int n = 0; n < 4; ++n) {
#pragma unroll
      for (int j = 0; j < 4; ++j) {
        const int row = rb + m * 16 + j;
        const int col = cb + n * 16;
        float v = acc[m][n][j];
        if constexpr (EPI == 2 || EPI == 3) v += bias[col];
        if constexpr (EPI == 2) v = 0.5f * v * (1.f + erff(v * 0.7071067811865475f));
        if constexpr (EPI == 1 || EPI == 3) v += resid[(size_t)row * N + col];
        if constexpr (EPI == 0 || EPI == 2)
          ((bf16*)Cout)[(size_t)row * N + col] = (bf16)v;
        else
          ((float*)Cout)[(size_t)row * N + col] = v;
      }
    }
  }
}

// ---------------- flash attention with chunk mask: key j allowed iff j <= q%1024 ----------------
// Keys >= 1024 are never attended. Within keys [0,1024) pattern is causal in r=q%1024.
__global__ __launch_bounds__(256) void attn_kernel(const bf16* __restrict__ qkv,
                                                   const bf16* __restrict__ vt,
                                                   bf16* __restrict__ attnout) {
  __shared__ float plds[4][16][32];
  const int t = threadIdx.x;
  const int wv = t >> 6, l = t & 63;
  const int lr = l & 15, lk = l >> 4;
  const int bh = blockIdx.y, b = bh >> 4, h = bh & 15;
  const int q0 = blockIdx.x * 64 + wv * 16;  // this wave's 16 queries
  const int rm0 = q0 & 1023;
  const float scale = 0.08838834764831845f;  // 1/sqrt(128)

  const bf16* qptr = qkv + (size_t)(b * Sq + q0 + lr) * (3 * Dm) + h * HDn + lk * 8;
  bf16x8 qf[4];
#pragma unroll
  for (int ks = 0; ks < 4; ++ks) qf[ks] = *(const bf16x8*)(qptr + ks * 32);

  const bf16* kbase = qkv + (size_t)(b * Sq) * (3 * Dm) + Dm + h * HDn + lk * 8;
  const bf16* vbase = vt + ((size_t)bh * HDn + lr) * Sq + lk * 8;

  f32x4 o[8] = {};
  f32x4 mrow = {-1e30f, -1e30f, -1e30f, -1e30f};
  f32x4 lrow = {0.f, 0.f, 0.f, 0.f};
  float* pw = &plds[wv][0][0];

  const int ntiles = (rm0 >> 5) + 1;
  for (int kt = 0; kt < ntiles; ++kt) {
    const bool maskt = (kt == ntiles - 1);
    f32x4 s[2];
#pragma unroll
    for (int n2 = 0; n2 < 2; ++n2) {
      f32x4 sa = {0.f, 0.f, 0.f, 0.f};
      const bf16* kp = kbase + (size_t)(kt * 32 + n2 * 16 + lr) * (3 * Dm);
#pragma unroll
      for (int ks = 0; ks < 4; ++ks)
        sa = __builtin_amdgcn_mfma_f32_16x16x32_bf16(qf[ks], *(const bf16x8*)(kp + ks * 32), sa, 0, 0, 0);
      s[n2] = sa;
    }
    // scale + mask (C layout: row = lk*4+j, col = n2*16+lr)
#pragma unroll
    for (int n2 = 0; n2 < 2; ++n2)
#pragma unroll
      for (int j = 0; j < 4; ++j) {
        float v = s[n2][j] * scale;
        if (maskt) {
          const int key = kt * 32 + n2 * 16 + lr;
          const int rmod = rm0 + lk * 4 + j;
          if (key > rmod) v = -1e30f;
        }
        s[n2][j] = v;
      }
    // row max over the 32-key tile
    f32x4 tm;
#pragma unroll
    for (int j = 0; j < 4; ++j) tm[j] = fmaxf(s[0][j], s[1][j]);
#pragma unroll
    for (int off = 1; off < 16; off <<= 1)
#pragma unroll
      for (int j = 0; j < 4; ++j) {
        float tv = tm[j];
        tm[j] = fmaxf(tv, __shfl_xor(tv, off));
      }
    f32x4 mnew, alpha, rs;
#pragma unroll
    for (int j = 0; j < 4; ++j) {
      mnew[j] = fmaxf(mrow[j], tm[j]);
      alpha[j] = __expf(mrow[j] - mnew[j]);
      rs[j] = 0.f;
    }
#pragma unroll
    for (int n2 = 0; n2 < 2; ++n2)
#pragma unroll
      for (int j = 0; j < 4; ++j) {
        const float p = __expf(s[n2][j] - mnew[j]);
        s[n2][j] = p;
        rs[j] += p;
      }
#pragma unroll
    for (int off = 1; off < 16; off <<= 1)
#pragma unroll
      for (int j = 0; j < 4; ++j) rs[j] += __shfl_xor(rs[j], off);
#pragma unroll
    for (int j = 0; j < 4; ++j) {
      lrow[j] = lrow[j] * alpha[j] + rs[j];
      mrow[j] = mnew[j];
    }
#pragma unroll
    for (int nt = 0; nt < 8; ++nt) o[nt] *= alpha;

    // transpose P via per-wave LDS (write C-layout, read A-frag layout)
#pragma unroll
    for (int n2 = 0; n2 < 2; ++n2)
#pragma unroll
      for (int j = 0; j < 4; ++j)
        pw[(lk * 4 + j) * 32 + n2 * 16 + lr] = s[n2][j];
    asm volatile("" ::: "memory");
    bf16x8 pa;
    const float* pr = pw + lr * 32 + lk * 8;
#pragma unroll
    for (int jj = 0; jj < 8; ++jj) pa[jj] = (bf16)pr[jj];
    asm volatile("" ::: "memory");

    // PV: o[q][d] += P[q][k] * V[k][d]
#pragma unroll
    for (int nt = 0; nt < 8; ++nt) {
      bf16x8 vf = *(const bf16x8*)(vbase + (size_t)nt * 16 * Sq + kt * 32);
      o[nt] = __builtin_amdgcn_mfma_f32_16x16x32_bf16(pa, vf, o[nt], 0, 0, 0);
    }
  }

  bf16* ob = attnout + (size_t)(b * Sq + q0) * Dm + h * HDn;
#pragma unroll
  for (int nt = 0; nt < 8; ++nt)
#pragma unroll
    for (int j = 0; j < 4; ++j)
      ob[(size_t)(lk * 4 + j) * Dm + nt * 16 + lr] = (bf16)(o[nt][j] / lrow[j]);
}

// ---------------- host launcher ----------------
extern "C" void kernel_launch(void* const* d_in, const int* in_sizes, int n_in,
                              void* d_out, int out_size, void* d_ws, size_t ws_size,
                              hipStream_t stream) {
  const float* x    = (const float*)d_in[0];
  const float* wqkv = (const float*)d_in[1];
  const float* wo   = (const float*)d_in[2];
  const float* w1   = (const float*)d_in[3];
  const float* b1   = (const float*)d_in[4];
  const float* w2   = (const float*)d_in[5];
  const float* b2   = (const float*)d_in[6];
  const float* g1   = (const float*)d_in[7];
  const float* be1  = (const float*)d_in[8];
  const float* g2   = (const float*)d_in[9];
  const float* be2  = (const float*)d_in[10];
  float* out = (float*)d_out;
  char* ws = (char*)d_ws;

  // workspace layout (bytes)
  const size_t OFF_WQKVT = 0;                         // [6144][2048] bf16 = 25165824
  const size_t OFF_WOT   = OFF_WQKVT + 25165824;      // [2048][2048] bf16 = 8388608
  const size_t OFF_W1T   = OFF_WOT   + 8388608;       // [8192][2048] bf16 = 33554432
  const size_t OFF_W2T   = OFF_W1T   + 33554432;      // [2048][8192] bf16 = 33554432
  const size_t OFF_H     = OFF_W2T   + 33554432;      // [4096][2048] bf16 = 16777216
  const size_t OFF_QKV   = OFF_H     + 16777216;      // [4096][6144] bf16 = 50331648
  const size_t OFF_VT    = OFF_QKV   + 50331648;      // [32][128][2048] bf16 = 16777216
  const size_t OFF_ATT   = OFF_VT    + 16777216;      // [4096][2048] bf16 = 16777216
  const size_t OFF_X1    = OFF_ATT   + 16777216;      // [4096][2048] f32  = 33554432
  const size_t OFF_G     = OFF_QKV;                   // gelu buf reuses qkv+vt (67108864)

  bf16* wqkvT = (bf16*)(ws + OFF_WQKVT);
  bf16* woT   = (bf16*)(ws + OFF_WOT);
  bf16* w1T   = (bf16*)(ws + OFF_W1T);
  bf16* w2T   = (bf16*)(ws + OFF_W2T);
  bf16* hbuf  = (bf16*)(ws + OFF_H);
  bf16* qkvb  = (bf16*)(ws + OFF_QKV);
  bf16* vtb   = (bf16*)(ws + OFF_VT);
  bf16* attb  = (bf16*)(ws + OFF_ATT);
  float* x1b  = (float*)(ws + OFF_X1);
  bf16* gbuf  = (bf16*)(ws + OFF_G);

  // weight convert+transpose to [N][K] bf16
  cvtT_kernel<<<dim3(192, 64), dim3(32, 8), 0, stream>>>(wqkv, wqkvT, 2048, 6144);
  cvtT_kernel<<<dim3(64, 64),  dim3(32, 8), 0, stream>>>(wo,   woT,   2048, 2048);
  cvtT_kernel<<<dim3(256, 64), dim3(32, 8), 0, stream>>>(w1,   w1T,   2048, 8192);
  cvtT_kernel<<<dim3(64, 256), dim3(32, 8), 0, stream>>>(w2,   w2T,   8192, 2048);

  // attention block
  ln_kernel<<<4096, 256, 0, stream>>>(x, g1, be1, hbuf);
  gemm_bt<0><<<dim3(32, 48), 256, 0, stream>>>(hbuf, wqkvT, qkvb, nullptr, nullptr, 4096, 6144, 2048);
  vtx_kernel<<<dim3(64, 4, 32), dim3(32, 8), 0, stream>>>(qkvb, vtb);
  attn_kernel<<<dim3(32, 32), 256, 0, stream>>>(qkvb, vtb, attb);
  gemm_bt<1><<<dim3(32, 16), 256, 0, stream>>>(attb, woT, x1b, nullptr, x, 4096, 2048, 2048);

  // MLP block
  ln_kernel<<<4096, 256, 0, stream>>>(x1b, g2, be2, hbuf);
  gemm_bt<2><<<dim3(32, 64), 256, 0, stream>>>(hbuf, w1T, gbuf, b1, nullptr, 4096, 8192, 2048);
  gemm_bt<3><<<dim3(32, 16), 256, 0, stream>>>(gbuf, w2T, out, b2, x1b, 4096, 2048, 8192);

  (void)in_sizes; (void)n_in; (void)out_size; (void)ws_size;
}

// Round 2
// 1095.084 us; speedup vs baseline: 1.0457x; 1.0457x over previous
//
#include <hip/hip_runtime.h>
#include <hip/hip_bf16.h>
#include <cstdint>
#include <cstddef>

typedef __bf16 bf16;
typedef __attribute__((ext_vector_type(8))) __bf16 bf16x8;
typedef __attribute__((ext_vector_type(4))) float f32x4;

static constexpr int Dm = 2048;   // model dim
static constexpr int Sq = 2048;   // seq len
static constexpr int Hn = 16;     // heads
static constexpr int HDn = 128;   // head dim
static constexpr int MR = 4096;   // B*S rows

// ---------------- async global->LDS (16B per lane) ----------------
__device__ __forceinline__ void gload_lds16(const void* gp, void* lp) {
  __builtin_amdgcn_global_load_lds(
      (__attribute__((address_space(1))) void*)(void*)gp,
      (__attribute__((address_space(3))) void*)lp,
      16, 0, 0);
}

// ---------------- LayerNorm: fp32 in -> bf16 out ----------------
__global__ __launch_bounds__(256) void ln_kernel(const float* __restrict__ x,
                                                 const float* __restrict__ g,
                                                 const float* __restrict__ be,
                                                 bf16* __restrict__ out) {
  const int row = blockIdx.x;
  const int t = threadIdx.x;
  const float* xr = x + (size_t)row * Dm;
  f32x4 a = *(const f32x4*)(xr + t * 8);
  f32x4 b = *(const f32x4*)(xr + t * 8 + 4);
  float s = 0.f, ss = 0.f;
#pragma unroll
  for (int i = 0; i < 4; i++) { s += a[i] + b[i]; ss += a[i]*a[i] + b[i]*b[i]; }
#pragma unroll
  for (int off = 32; off > 0; off >>= 1) { s += __shfl_xor(s, off); ss += __shfl_xor(ss, off); }
  __shared__ float ls[4], lss[4];
  if ((t & 63) == 0) { ls[t >> 6] = s; lss[t >> 6] = ss; }
  __syncthreads();
  s = ls[0] + ls[1] + ls[2] + ls[3];
  ss = lss[0] + lss[1] + lss[2] + lss[3];
  const float mean = s * (1.f / Dm);
  const float rstd = rsqrtf(ss * (1.f / Dm) - mean * mean + 1e-5f);
  f32x4 g0 = *(const f32x4*)(g + t * 8);
  f32x4 g1 = *(const f32x4*)(g + t * 8 + 4);
  f32x4 b0 = *(const f32x4*)(be + t * 8);
  f32x4 b1 = *(const f32x4*)(be + t * 8 + 4);
  bf16x8 o;
#pragma unroll
  for (int i = 0; i < 4; i++) {
    o[i]     = (bf16)((a[i] - mean) * rstd * g0[i] + b0[i]);
    o[i + 4] = (bf16)((b[i] - mean) * rstd * g1[i] + b1[i]);
  }
  *(bf16x8*)(out + (size_t)row * Dm + t * 8) = o;
}

// ------------- transpose + fp32->bf16 convert: out[c][r] = in[r][c] -------------
__global__ void cvtT_kernel(const float* __restrict__ in, bf16* __restrict__ out,
                            int R, int C) {
  __shared__ float tile[32][33];
  const int c0 = blockIdx.x * 32, r0 = blockIdx.y * 32;
  const int tx = threadIdx.x, ty = threadIdx.y;
#pragma unroll
  for (int i = 0; i < 4; i++)
    tile[ty + i * 8][tx] = in[(size_t)(r0 + ty + i * 8) * C + c0 + tx];
  __syncthreads();
#pragma unroll
  for (int i = 0; i < 4; i++)
    out[(size_t)(c0 + ty + i * 8) * R + r0 + tx] = (bf16)tile[tx][ty + i * 8];
}

// ------------- extract V^T per (b,h), keys s<1024 only: vt[bh][d][s] -------------
__global__ void vtx_kernel(const bf16* __restrict__ qkv, bf16* __restrict__ vt) {
  __shared__ bf16 tile[32][33];
  const int s0 = blockIdx.x * 32;   // 0..1023
  const int d0 = blockIdx.y * 32;
  const int bh = blockIdx.z;
  const int b = bh >> 4, h = bh & 15;
  const int tx = threadIdx.x, ty = threadIdx.y;
#pragma unroll
  for (int i = 0; i < 4; i++)
    tile[ty + i * 8][tx] =
        qkv[(size_t)(b * Sq + s0 + ty + i * 8) * (3 * Dm) + 2 * Dm + h * HDn + d0 + tx];
  __syncthreads();
#pragma unroll
  for (int i = 0; i < 4; i++)
    vt[((size_t)bh * HDn + d0 + ty + i * 8) * 1024 + s0 + tx] = tile[tx][ty + i * 8];
}

// ---------------- GEMM: C[M,N] = A[M,K](bf16) @ BT[N,K](bf16), fused epilogues ----------------
// EPI 0: store bf16
// EPI 1: + resid(fp32), store fp32
// EPI 2: + bias, exact GELU, store bf16
// EPI 3: + bias + resid, store fp32
template <int EPI>
__global__ __launch_bounds__(256) void gemm_bt(const bf16* __restrict__ A,
                                               const bf16* __restrict__ BT,
                                               void* __restrict__ Cout,
                                               const float* __restrict__ bias,
                                               const float* __restrict__ resid,
                                               int M, int N, int K) {
  __shared__ alignas(16) bf16 As[128 * 32];
  __shared__ alignas(16) bf16 Bs[128 * 32];
  const int t = threadIdx.x;
  const int l = t & 63;
  const int wv = t >> 6, wr = wv >> 1, wc = wv & 1;
  const int lr = l & 15, lk = l >> 4;
  // XCD-aware bijective swizzle (nwg % 8 == 0 for all our grids)
  const int gx = gridDim.x, gy = gridDim.y;
  const int nwg = gx * gy;
  int id = blockIdx.y * gx + blockIdx.x;
  id = (id & 7) * (nwg >> 3) + (id >> 3);
  const int m0 = (id % gx) * 128, n0 = (id / gx) * 128;
  f32x4 acc[4][4] = {};

  const int ar = t >> 2;            // staging row within tile (0..63)
  const int ak = (t & 3) << 3;      // staging k offset (bf16 elems)
  const bf16* Ag  = A  + (size_t)(m0 + ar) * K + ak;
  const bf16* Ag2 = Ag + (size_t)64 * K;
  const bf16* Bg  = BT + (size_t)(n0 + ar) * K + ak;
  const bf16* Bg2 = Bg + (size_t)64 * K;
  bf16* Asd  = As + t * 8;
  bf16* Asd2 = As + 2048 + t * 8;
  bf16* Bsd  = Bs + t * 8;
  bf16* Bsd2 = Bs + 2048 + t * 8;

  const int nk = K >> 5;
  for (int kt = 0; kt < nk; ++kt) {
    gload_lds16(Ag, Asd);
    gload_lds16(Ag2, Asd2);
    gload_lds16(Bg, Bsd);
    gload_lds16(Bg2, Bsd2);
    Ag += 32; Ag2 += 32; Bg += 32; Bg2 += 32;
    __syncthreads();
    bf16x8 af[4], bfr[4];
#pragma unroll
    for (int m = 0; m < 4; ++m)
      af[m] = *(const bf16x8*)(As + (wr * 64 + m * 16 + lr) * 32 + lk * 8);
#pragma unroll
    for (int n = 0; n < 4; ++n)
      bfr[n] = *(const bf16x8*)(Bs + (wc * 64 + n * 16 + lr) * 32 + lk * 8);
#pragma unroll
    for (int m = 0; m < 4; ++m)
#pragma unroll
      for (int n = 0; n < 4; ++n)
        acc[m][n] = __builtin_amdgcn_mfma_f32_16x16x32_bf16(af[m], bfr[n], acc[m][n], 0, 0, 0);
    __syncthreads();
  }

  const int rb = m0 + wr * 64 + lk * 4;  // + m*16 + j
  const int cb = n0 + wc * 64 + lr;      // + n*16
#pragma unroll
  for (int m = 0; m < 4; ++m) {
#pragma unroll
    for (int n = 0; n < 4; ++n) {
#pragma unroll
      for (int j = 0; j < 4; ++j) {
        const int row = rb + m * 16 + j;
        const int col = cb + n * 16;
        float v = acc[m][n][j];
        if constexpr (EPI == 2 || EPI == 3) v += bias[col];
        if constexpr (EPI == 2) v = 0.5f * v * (1.f + erff(v * 0.7071067811865475f));
        if constexpr (EPI == 1 || EPI == 3) v += resid[(size_t)row * N + col];
        if constexpr (EPI == 0 || EPI == 2)
          ((bf16*)Cout)[(size_t)row * N + col] = (bf16)v;
        else
          ((float*)Cout)[(size_t)row * N + col] = v;
      }
    }
  }
}

// ---------------- flash attention, chunk mask: key j allowed iff j <= q%1024 ----------------
// Swapped QK^T: D[key][query], query = lane&15. Softmax reductions in-lane + 2 shfl.
// P redistribution to PV A-frag via 8 shfl (no LDS). Defer-max (THR=8) skips O-rescale.
// Load balance: waves handle query-tile pair (u, 63-u) so every block has equal work.
__global__ __launch_bounds__(256) void attn_kernel(const bf16* __restrict__ qkv,
                                                   const bf16* __restrict__ vt,
                                                   bf16* __restrict__ attnout) {
  const int t = threadIdx.x;
  const int wv = t >> 6, l = t & 63;
  const int lr = l & 15, lk = l >> 4;
  const int bh = blockIdx.y, b = bh >> 4, h = bh & 15;
  const int pp = blockIdx.x * 2 + (wv >> 1);
  const int c = pp >> 5, pb = pp & 31;
  const int u = (wv & 1) ? (63 - pb) : pb;   // query tile index within chunk (16 q each)
  const int q0 = c * 1024 + u * 16;
  const int rm0 = u * 16;                    // q%1024 of first query
  const float scale = 0.08838834764831845f;  // 1/sqrt(128)

  // Q frags (B-operand), scale folded in: qf[ks] = Q[q0+lr][ks*32+lk*8+i]*scale
  const bf16* qptr = qkv + (size_t)(b * Sq + q0 + lr) * (3 * Dm) + h * HDn + lk * 8;
  bf16x8 qf[4];
#pragma unroll
  for (int ks = 0; ks < 4; ++ks) {
    bf16x8 r = *(const bf16x8*)(qptr + ks * 32);
#pragma unroll
    for (int i = 0; i < 8; ++i) r[i] = (bf16)((float)r[i] * scale);
    qf[ks] = r;
  }

  const bf16* kbase = qkv + (size_t)(b * Sq) * (3 * Dm) + Dm + h * HDn + lk * 8;
  const bf16* vbase = vt + ((size_t)bh * HDn + lr) * 1024 + lk * 8;

  f32x4 o[8] = {};       // D[row=query lk*4+j][col=d nt*16+lr]
  float m = 0.f, lsum = 0.f;   // per-lane state for query lr

  const int ntiles = (rm0 >> 5) + 1;
  for (int kt = 0; kt < ntiles; ++kt) {
    // K frags (A-operand): kf[n2][ks] = K[kt*32+n2*16+lr][ks*32+lk*8+i]
    const bf16* kp0 = kbase + (size_t)(kt * 32 + lr) * (3 * Dm);
    const bf16* kp1 = kp0 + (size_t)16 * (3 * Dm);
    bf16x8 kf0[4], kf1[4];
#pragma unroll
    for (int ks = 0; ks < 4; ++ks) {
      kf0[ks] = *(const bf16x8*)(kp0 + ks * 32);
      kf1[ks] = *(const bf16x8*)(kp1 + ks * 32);
    }
    f32x4 s0 = {0.f, 0.f, 0.f, 0.f}, s1 = {0.f, 0.f, 0.f, 0.f};
#pragma unroll
    for (int ks = 0; ks < 4; ++ks) {
      s0 = __builtin_amdgcn_mfma_f32_16x16x32_bf16(kf0[ks], qf[ks], s0, 0, 0, 0);
      s1 = __builtin_amdgcn_mfma_f32_16x16x32_bf16(kf1[ks], qf[ks], s1, 0, 0, 0);
    }
    // D layout: row = key = n2*16 + lk*4 + j (n2: s0/s1), col = query = lr
    if (kt == ntiles - 1) {
      const int kb = kt * 32 + lk * 4;
      const int r = rm0 + lr;
#pragma unroll
      for (int j = 0; j < 4; ++j) {
        if (kb + j > r)      s0[j] = -1e30f;
        if (kb + 16 + j > r) s1[j] = -1e30f;
      }
    }
    // per-query max over this 32-key tile: 8 in-lane + lanes {lr, lr+16, lr+32, lr+48}
    float tmax = fmaxf(fmaxf(fmaxf(s0[0], s0[1]), fmaxf(s0[2], s0[3])),
                       fmaxf(fmaxf(s1[0], s1[1]), fmaxf(s1[2], s1[3])));
    tmax = fmaxf(tmax, __shfl_xor(tmax, 16));
    tmax = fmaxf(tmax, __shfl_xor(tmax, 32));
    if (__builtin_expect(__any(tmax > m + 8.f), 0)) {
      const float mnew = fmaxf(m, tmax);
      const float alpha = __expf(m - mnew);
      m = mnew;
      lsum *= alpha;
      float aq[4];
#pragma unroll
      for (int j = 0; j < 4; ++j) aq[j] = __shfl(alpha, lk * 4 + j);
#pragma unroll
      for (int nt = 0; nt < 8; ++nt)
#pragma unroll
        for (int j = 0; j < 4; ++j) o[nt][j] *= aq[j];
    }
    // p = exp(s - m); row sum; pack to bf16
    float rs = 0.f;
    union { bf16x8 v; uint32_t uu[4]; } pk;
#pragma unroll
    for (int j = 0; j < 4; ++j) {
      const float p0 = __expf(s0[j] - m);
      const float p1 = __expf(s1[j] - m);
      rs += p0 + p1;
      pk.v[j] = (bf16)p0;      // uu[0]=keys{4lk,4lk+1}, uu[1]={4lk+2,4lk+3}
      pk.v[4 + j] = (bf16)p1;  // uu[2]={16+4lk,..}, uu[3]={16+4lk+2,..}
    }
    rs += __shfl_xor(rs, 16);
    rs += __shfl_xor(rs, 32);
    lsum += rs;
    // redistribute P -> PV A-frag: dest lane (lr,lk) needs keys 8lk..8lk+7 of query lr
    const int sA = lr + 16 * ((2 * lk) & 3);
    const int sB = lr + 16 * ((2 * lk + 1) & 3);
    const bool hi2 = ((lk >> 1) & 1) != 0;
    const uint32_t A0 = (uint32_t)__shfl((int)pk.uu[0], sA);
    const uint32_t A1 = (uint32_t)__shfl((int)pk.uu[1], sA);
    const uint32_t A2 = (uint32_t)__shfl((int)pk.uu[2], sA);
    const uint32_t A3 = (uint32_t)__shfl((int)pk.uu[3], sA);
    const uint32_t B0 = (uint32_t)__shfl((int)pk.uu[0], sB);
    const uint32_t B1 = (uint32_t)__shfl((int)pk.uu[1], sB);
    const uint32_t B2 = (uint32_t)__shfl((int)pk.uu[2], sB);
    const uint32_t B3 = (uint32_t)__shfl((int)pk.uu[3], sB);
    union { bf16x8 v; uint32_t uu[4]; } pa;
    pa.uu[0] = hi2 ? A2 : A0;
    pa.uu[1] = hi2 ? A3 : A1;
    pa.uu[2] = hi2 ? B2 : B0;
    pa.uu[3] = hi2 ? B3 : B1;
    // PV: o[q][d] += P[q][k] * V[k][d]
#pragma unroll
    for (int nt = 0; nt < 8; ++nt) {
      bf16x8 vf = *(const bf16x8*)(vbase + (size_t)nt * 16 * 1024 + kt * 32);
      o[nt] = __builtin_amdgcn_mfma_f32_16x16x32_bf16(pa.v, vf, o[nt], 0, 0, 0);
    }
  }
  // normalize + write: out row = q0 + lk*4+j, col = h*128 + nt*16 + lr
  const float rinv = 1.f / lsum;
  float rq[4];
#pragma unroll
  for (int j = 0; j < 4; ++j) rq[j] = __shfl(rinv, lk * 4 + j);
  bf16* ob = attnout + (size_t)(b * Sq + q0) * Dm + h * HDn;
#pragma unroll
  for (int nt = 0; nt < 8; ++nt)
#pragma unroll
    for (int j = 0; j < 4; ++j)
      ob[(size_t)(lk * 4 + j) * Dm + nt * 16 + lr] = (bf16)(o[nt][j] * rq[j]);
}

// ---------------- host launcher ----------------
extern "C" void kernel_launch(void* const* d_in, const int* in_sizes, int n_in,
                              void* d_out, int out_size, void* d_ws, size_t ws_size,
                              hipStream_t stream) {
  const float* x    = (const float*)d_in[0];
  const float* wqkv = (const float*)d_in[1];
  const float* wo   = (const float*)d_in[2];
  const float* w1   = (const float*)d_in[3];
  const float* b1   = (const float*)d_in[4];
  const float* w2   = (const float*)d_in[5];
  const float* b2   = (const float*)d_in[6];
  const float* g1   = (const float*)d_in[7];
  const float* be1  = (const float*)d_in[8];
  const float* g2   = (const float*)d_in[9];
  const float* be2  = (const float*)d_in[10];
  float* out = (float*)d_out;
  char* ws = (char*)d_ws;

  // workspace layout (bytes)
  const size_t OFF_WQKVT = 0;                         // [6144][2048] bf16 = 25165824
  const size_t OFF_WOT   = OFF_WQKVT + 25165824;      // [2048][2048] bf16 = 8388608
  const size_t OFF_W1T   = OFF_WOT   + 8388608;       // [8192][2048] bf16 = 33554432
  const size_t OFF_W2T   = OFF_W1T   + 33554432;      // [2048][8192] bf16 = 33554432
  const size_t OFF_H     = OFF_W2T   + 33554432;      // [4096][2048] bf16 = 16777216
  const size_t OFF_QKV   = OFF_H     + 16777216;      // [4096][6144] bf16 = 50331648
  const size_t OFF_VT    = OFF_QKV   + 50331648;      // [32][128][1024] bf16 (8MB used of 16MB)
  const size_t OFF_ATT   = OFF_VT    + 16777216;      // [4096][2048] bf16 = 16777216
  const size_t OFF_X1    = OFF_ATT   + 16777216;      // [4096][2048] f32  = 33554432
  const size_t OFF_G     = OFF_QKV;                   // gelu buf reuses qkv+vt (64MB)

  bf16* wqkvT = (bf16*)(ws + OFF_WQKVT);
  bf16* woT   = (bf16*)(ws + OFF_WOT);
  bf16* w1T   = (bf16*)(ws + OFF_W1T);
  bf16* w2T   = (bf16*)(ws + OFF_W2T);
  bf16* hbuf  = (bf16*)(ws + OFF_H);
  bf16* qkvb  = (bf16*)(ws + OFF_QKV);
  bf16* vtb   = (bf16*)(ws + OFF_VT);
  bf16* attb  = (bf16*)(ws + OFF_ATT);
  float* x1b  = (float*)(ws + OFF_X1);
  bf16* gbuf  = (bf16*)(ws + OFF_G);

  // weight convert+transpose to [N][K] bf16
  cvtT_kernel<<<dim3(192, 64), dim3(32, 8), 0, stream>>>(wqkv, wqkvT, 2048, 6144);
  cvtT_kernel<<<dim3(64, 64),  dim3(32, 8), 0, stream>>>(wo,   woT,   2048, 2048);
  cvtT_kernel<<<dim3(256, 64), dim3(32, 8), 0, stream>>>(w1,   w1T,   2048, 8192);
  cvtT_kernel<<<dim3(64, 256), dim3(32, 8), 0, stream>>>(w2,   w2T,   8192, 2048);

  // attention block
  ln_kernel<<<4096, 256, 0, stream>>>(x, g1, be1, hbuf);
  gemm_bt<0><<<dim3(32, 48), 256, 0, stream>>>(hbuf, wqkvT, qkvb, nullptr, nullptr, 4096, 6144, 2048);
  vtx_kernel<<<dim3(32, 4, 32), dim3(32, 8), 0, stream>>>(qkvb, vtb);
  attn_kernel<<<dim3(32, 32), 256, 0, stream>>>(qkvb, vtb, attb);
  gemm_bt<1><<<dim3(32, 16), 256, 0, stream>>>(attb, woT, x1b, nullptr, x, 4096, 2048, 2048);

  // MLP block
  ln_kernel<<<4096, 256, 0, stream>>>(x1b, g2, be2, hbuf);
  gemm_bt<2><<<dim3(32, 64), 256, 0, stream>>>(hbuf, w1T, gbuf, b1, nullptr, 4096, 8192, 2048);
  gemm_bt<3><<<dim3(32, 16), 256, 0, stream>>>(gbuf, w2T, out, b2, x1b, 4096, 2048, 8192);

  (void)in_sizes; (void)n_in; (void)out_size; (void)ws_size;
}

// Round 4
// 896.728 us; speedup vs baseline: 1.2770x; 1.2212x over previous
//
#include <hip/hip_runtime.h>
#include <hip/hip_bf16.h>
#include <cstdint>
#include <cstddef>

typedef __bf16 bf16;
typedef __attribute__((ext_vector_type(8))) __bf16 bf16x8;
typedef __attribute__((ext_vector_type(4))) float f32x4;

static constexpr int Dm = 2048;   // model dim
static constexpr int Sq = 2048;   // seq len
static constexpr int HDn = 128;   // head dim

#define BARX() asm volatile("s_barrier" ::: "memory")
#define WAITV2() asm volatile("s_waitcnt vmcnt(2)" ::: "memory")
#define WAITV0() asm volatile("s_waitcnt vmcnt(0)" ::: "memory")

// ---------------- async global->LDS (16B per lane) ----------------
__device__ __forceinline__ void gload_lds16(const void* gp, void* lp) {
  __builtin_amdgcn_global_load_lds(
      (__attribute__((address_space(1))) void*)(void*)gp,
      (__attribute__((address_space(3))) void*)lp,
      16, 0, 0);
}

// ---------------- LayerNorm: fp32 in -> bf16 out ----------------
__global__ __launch_bounds__(256) void ln_kernel(const float* __restrict__ x,
                                                 const float* __restrict__ g,
                                                 const float* __restrict__ be,
                                                 bf16* __restrict__ out) {
  const int row = blockIdx.x;
  const int t = threadIdx.x;
  const float* xr = x + (size_t)row * Dm;
  f32x4 a = *(const f32x4*)(xr + t * 8);
  f32x4 b = *(const f32x4*)(xr + t * 8 + 4);
  float s = 0.f, ss = 0.f;
#pragma unroll
  for (int i = 0; i < 4; i++) { s += a[i] + b[i]; ss += a[i]*a[i] + b[i]*b[i]; }
#pragma unroll
  for (int off = 32; off > 0; off >>= 1) { s += __shfl_xor(s, off); ss += __shfl_xor(ss, off); }
  __shared__ float ls[4], lss[4];
  if ((t & 63) == 0) { ls[t >> 6] = s; lss[t >> 6] = ss; }
  __syncthreads();
  s = ls[0] + ls[1] + ls[2] + ls[3];
  ss = lss[0] + lss[1] + lss[2] + lss[3];
  const float mean = s * (1.f / Dm);
  const float rstd = rsqrtf(ss * (1.f / Dm) - mean * mean + 1e-5f);
  f32x4 g0 = *(const f32x4*)(g + t * 8);
  f32x4 g1 = *(const f32x4*)(g + t * 8 + 4);
  f32x4 b0 = *(const f32x4*)(be + t * 8);
  f32x4 b1 = *(const f32x4*)(be + t * 8 + 4);
  bf16x8 o;
#pragma unroll
  for (int i = 0; i < 4; i++) {
    o[i]     = (bf16)((a[i] - mean) * rstd * g0[i] + b0[i]);
    o[i + 4] = (bf16)((b[i] - mean) * rstd * g1[i] + b1[i]);
  }
  *(bf16x8*)(out + (size_t)row * Dm + t * 8) = o;
}

// ------------- transpose + fp32->bf16 convert: out[c][r] = in[r][c] -------------
__global__ void cvtT_kernel(const float* __restrict__ in, bf16* __restrict__ out,
                            int R, int C) {
  __shared__ float tile[32][33];
  const int c0 = blockIdx.x * 32, r0 = blockIdx.y * 32;
  const int tx = threadIdx.x, ty = threadIdx.y;
#pragma unroll
  for (int i = 0; i < 4; i++)
    tile[ty + i * 8][tx] = in[(size_t)(r0 + ty + i * 8) * C + c0 + tx];
  __syncthreads();
#pragma unroll
  for (int i = 0; i < 4; i++)
    out[(size_t)(c0 + ty + i * 8) * R + r0 + tx] = (bf16)tile[tx][ty + i * 8];
}

// ------------- extract V^T per (b,h), keys s<1024 only: vt[bh][d][s] -------------
__global__ void vtx_kernel(const bf16* __restrict__ qkv, bf16* __restrict__ vt) {
  __shared__ bf16 tile[32][33];
  const int s0 = blockIdx.x * 32;   // 0..1023
  const int d0 = blockIdx.y * 32;
  const int bh = blockIdx.z;
  const int b = bh >> 4, h = bh & 15;
  const int tx = threadIdx.x, ty = threadIdx.y;
#pragma unroll
  for (int i = 0; i < 4; i++)
    tile[ty + i * 8][tx] =
        qkv[(size_t)(b * Sq + s0 + ty + i * 8) * (3 * Dm) + 2 * Dm + h * HDn + d0 + tx];
  __syncthreads();
#pragma unroll
  for (int i = 0; i < 4; i++)
    vt[((size_t)bh * HDn + d0 + ty + i * 8) * 1024 + s0 + tx] = tile[tx][ty + i * 8];
}

// =====================================================================
// 8-phase 256-tile GEMM: C[M,N] = A[M,K](bf16) @ BT[N,K](bf16)
// BM=256, BN=256 or 128, BK=64, 512 threads (8 waves, 2x4).
// Double-buffered LDS, XOR bank swizzle (both sides, rule #21),
// counted vmcnt published wait->barrier->read (m201 invariant),
// setprio around MFMA clusters.
// EPI 0: store bf16; 1: +resid, fp32; 2: +bias, GELU, bf16; 3: +bias+resid, fp32
// =====================================================================
template <int BN, int EPI>
__global__ __launch_bounds__(512, 2) void gemm8p(const bf16* __restrict__ A,
                                                 const bf16* __restrict__ BT,
                                                 void* __restrict__ Cout,
                                                 const float* __restrict__ bias,
                                                 const float* __restrict__ resid,
                                                 int M, int N, int K) {
  constexpr int NI  = BN / 64;   // n-frags per wave (4 or 2); also # B chunks
  constexpr int NI2 = NI / 2;    // per-quadrant n-frags (2 or 1)
  constexpr int BSTR = BN * 128; // per-buffer B bytes
  __shared__ alignas(16) char smem[65536 + 2 * BSTR];
  char* const As_ = smem;
  char* const Bs_ = smem + 65536;

  const int t = threadIdx.x;
  const int l = t & 63;
  const int lr = l & 15, lk = l >> 4;
  const int wv = t >> 6, wr = wv >> 2, wc = wv & 3;

  // XCD-aware bijective swizzle (all grids have nwg % 8 == 0)
  const int gx = gridDim.x;
  const int nwg = gx * gridDim.y;
  int id = blockIdx.y * gx + blockIdx.x;
  id = (id & 7) * (nwg >> 3) + (id >> 3);
  const int m0 = (id % gx) * 256;
  const int n0 = (id / gx) * BN;

  // read-side lane bases: 16B-slot within row = (4b + (lk^(lr&3))), data slot
  // = addr_slot ^ (lr&7); koff pair selects K-subtile 0 then 1 for all lanes.
  const int swz = 16 * (lk ^ (lr & 3));
  const int b2 = (lr >> 2) & 1;
  const int k0off = 64 * b2;
  const int k1off = 64 - 64 * b2;
  char* const Ard = As_ + wr * 16384 + lr * 128 + swz;
  char* const Brd = Bs_ + (BN == 256 ? ((wc >> 1) * 16384 + (wc & 1) * 8192)
                                     : wc * 4096) + lr * 128 + swz;

  // stage-side: thread t stages 16B; source col pre-permuted (rule #21)
  const int trow = t >> 3;                       // 0..63
  const int scol = 8 * ((t & 7) ^ (trow & 7));   // bf16 col within 64-wide K-tile
  const bf16* const Asrc = A + (size_t)(m0 + trow) * K + scol;
  const bf16* const Bsrc = BT + (size_t)(n0 + trow) * K + scol;
  char* const Adst = As_ + t * 16;
  char* const Bdst = Bs_ + t * 16;

  f32x4 acc[8][NI];
#pragma unroll
  for (int i = 0; i < 8; ++i)
#pragma unroll
    for (int j = 0; j < NI; ++j) acc[i][j] = (f32x4){0.f, 0.f, 0.f, 0.f};

  const int nt = K >> 6;

  // prologue: stage tile 0 into buf 0, drain, publish
#pragma unroll
  for (int ch = 0; ch < 4; ++ch)
    gload_lds16(Asrc + (size_t)ch * 64 * K, Adst + ch * 8192);
#pragma unroll
  for (int ch = 0; ch < NI; ++ch)
    gload_lds16(Bsrc + (size_t)ch * 64 * K, Bdst + ch * 8192);
  WAITV0();
  BARX();

  int buf = 0;
  for (int kt = 0; kt < nt; ++kt, buf ^= 1) {
    const int nb = buf ^ 1;
    const bool pf = (kt + 1) < nt;
    const size_t kg = (size_t)(kt + 1) * 64;
    char* const Ard_b  = Ard + buf * 32768;
    char* const Brd_b  = Brd + buf * BSTR;
    char* const Adst_b = Adst + nb * 32768;
    char* const Bdst_b = Bdst + nb * BSTR;
    bf16x8 a0[4][2], a1[4][2], b0[NI2][2], b1[NI2][2];

    // ---------- q0: read aLo+bLo, stage {A0,A2}, MFMA lo x lo ----------
#pragma unroll
    for (int mi = 0; mi < 4; ++mi) {
      a0[mi][0] = *(const bf16x8*)(Ard_b + mi * 2048 + k0off);
      a0[mi][1] = *(const bf16x8*)(Ard_b + mi * 2048 + k1off);
    }
#pragma unroll
    for (int ni = 0; ni < NI2; ++ni) {
      b0[ni][0] = *(const bf16x8*)(Brd_b + ni * 2048 + k0off);
      b0[ni][1] = *(const bf16x8*)(Brd_b + ni * 2048 + k1off);
    }
    if (pf) {
      gload_lds16(Asrc + kg, Adst_b);
      gload_lds16(Asrc + (size_t)128 * K + kg, Adst_b + 2 * 8192);
    }
    BARX();
    __builtin_amdgcn_s_setprio(1);
#pragma unroll
    for (int mi = 0; mi < 4; ++mi)
#pragma unroll
      for (int ni = 0; ni < NI2; ++ni) {
        acc[mi][ni] = __builtin_amdgcn_mfma_f32_16x16x32_bf16(a0[mi][0], b0[ni][0], acc[mi][ni], 0, 0, 0);
        acc[mi][ni] = __builtin_amdgcn_mfma_f32_16x16x32_bf16(a0[mi][1], b0[ni][1], acc[mi][ni], 0, 0, 0);
      }
    __builtin_amdgcn_s_setprio(0);
    // publish prev tile's {A1,A3} (retire all but the 2 loads just issued)
    if (pf) { WAITV2(); } else { WAITV0(); }
    BARX();

    // ---------- q1: read aHi, stage {B0,B1}, MFMA hi x lo ----------
#pragma unroll
    for (int mi = 0; mi < 4; ++mi) {
      a1[mi][0] = *(const bf16x8*)(Ard_b + (4 + mi) * 2048 + k0off);
      a1[mi][1] = *(const bf16x8*)(Ard_b + (4 + mi) * 2048 + k1off);
    }
    if (pf) {
      gload_lds16(Bsrc + kg, Bdst_b);
      gload_lds16(Bsrc + (size_t)64 * K + kg, Bdst_b + 8192);
    }
    BARX();
    __builtin_amdgcn_s_setprio(1);
#pragma unroll
    for (int mi = 0; mi < 4; ++mi)
#pragma unroll
      for (int ni = 0; ni < NI2; ++ni) {
        acc[4 + mi][ni] = __builtin_amdgcn_mfma_f32_16x16x32_bf16(a1[mi][0], b0[ni][0], acc[4 + mi][ni], 0, 0, 0);
        acc[4 + mi][ni] = __builtin_amdgcn_mfma_f32_16x16x32_bf16(a1[mi][1], b0[ni][1], acc[4 + mi][ni], 0, 0, 0);
      }
    __builtin_amdgcn_s_setprio(0);
    BARX();

    // ---------- q2: read bHi, stage {B2,B3}|{A1,A3}, MFMA lo x hi ----------
#pragma unroll
    for (int ni = 0; ni < NI2; ++ni) {
      b1[ni][0] = *(const bf16x8*)(Brd_b + (NI2 + ni) * 2048 + k0off);
      b1[ni][1] = *(const bf16x8*)(Brd_b + (NI2 + ni) * 2048 + k1off);
    }
    if (pf) {
      if (BN == 256) {
        gload_lds16(Bsrc + (size_t)128 * K + kg, Bdst_b + 2 * 8192);
        gload_lds16(Bsrc + (size_t)192 * K + kg, Bdst_b + 3 * 8192);
      } else {
        gload_lds16(Asrc + (size_t)64 * K + kg, Adst_b + 8192);
        gload_lds16(Asrc + (size_t)192 * K + kg, Adst_b + 3 * 8192);
      }
    }
    BARX();
    __builtin_amdgcn_s_setprio(1);
#pragma unroll
    for (int mi = 0; mi < 4; ++mi)
#pragma unroll
      for (int ni = 0; ni < NI2; ++ni) {
        acc[mi][NI2 + ni] = __builtin_amdgcn_mfma_f32_16x16x32_bf16(a0[mi][0], b1[ni][0], acc[mi][NI2 + ni], 0, 0, 0);
        acc[mi][NI2 + ni] = __builtin_amdgcn_mfma_f32_16x16x32_bf16(a0[mi][1], b1[ni][1], acc[mi][NI2 + ni], 0, 0, 0);
      }
    __builtin_amdgcn_s_setprio(0);
    BARX();

    // ---------- q3: stage {A1,A3} (BN=256), MFMA hi x hi ----------
    if (pf && BN == 256) {
      gload_lds16(Asrc + (size_t)64 * K + kg, Adst_b + 8192);
      gload_lds16(Asrc + (size_t)192 * K + kg, Adst_b + 3 * 8192);
    }
    BARX();
    __builtin_amdgcn_s_setprio(1);
#pragma unroll
    for (int mi = 0; mi < 4; ++mi)
#pragma unroll
      for (int ni = 0; ni < NI2; ++ni) {
        acc[4 + mi][NI2 + ni] = __builtin_amdgcn_mfma_f32_16x16x32_bf16(a1[mi][0], b1[ni][0], acc[4 + mi][NI2 + ni], 0, 0, 0);
        acc[4 + mi][NI2 + ni] = __builtin_amdgcn_mfma_f32_16x16x32_bf16(a1[mi][1], b1[ni][1], acc[4 + mi][NI2 + ni], 0, 0, 0);
      }
    __builtin_amdgcn_s_setprio(0);
    // publish this tile's {A0,A2,B*} for next q0 (keep newest 2 = {A1,A3})
    WAITV2();
    BARX();
  }

  // ---------------- epilogue ----------------
  const int rb = m0 + wr * 128 + lk * 4;
  const int cb = n0 + wc * (BN / 4) + lr;
#pragma unroll
  for (int mi = 0; mi < 8; ++mi) {
#pragma unroll
    for (int ni = 0; ni < NI; ++ni) {
#pragma unroll
      for (int j = 0; j < 4; ++j) {
        const int row = rb + mi * 16 + j;
        const int col = cb + ni * 16;
        float v = acc[mi][ni][j];
        if constexpr (EPI == 2 || EPI == 3) v += bias[col];
        if constexpr (EPI == 2) v = 0.5f * v * (1.f + erff(v * 0.7071067811865475f));
        if constexpr (EPI == 1 || EPI == 3) v += resid[(size_t)row * N + col];
        if constexpr (EPI == 0 || EPI == 2)
          ((bf16*)Cout)[(size_t)row * N + col] = (bf16)v;
        else
          ((float*)Cout)[(size_t)row * N + col] = v;
      }
    }
  }
}

// ---------------- flash attention, chunk mask: key j allowed iff j <= q%1024 ----------------
__global__ __launch_bounds__(256) void attn_kernel(const bf16* __restrict__ qkv,
                                                   const bf16* __restrict__ vt,
                                                   bf16* __restrict__ attnout) {
  const int t = threadIdx.x;
  const int wv = t >> 6, l = t & 63;
  const int lr = l & 15, lk = l >> 4;
  const int bh = blockIdx.y, b = bh >> 4, h = bh & 15;
  const int pp = blockIdx.x * 2 + (wv >> 1);
  const int c = pp >> 5, pb = pp & 31;
  const int u = (wv & 1) ? (63 - pb) : pb;   // query tile index within chunk (16 q each)
  const int q0 = c * 1024 + u * 16;
  const int rm0 = u * 16;                    // q%1024 of first query
  const float scale = 0.08838834764831845f;  // 1/sqrt(128)

  const bf16* qptr = qkv + (size_t)(b * Sq + q0 + lr) * (3 * Dm) + h * HDn + lk * 8;
  bf16x8 qf[4];
#pragma unroll
  for (int ks = 0; ks < 4; ++ks) {
    bf16x8 r = *(const bf16x8*)(qptr + ks * 32);
#pragma unroll
    for (int i = 0; i < 8; ++i) r[i] = (bf16)((float)r[i] * scale);
    qf[ks] = r;
  }

  const bf16* kbase = qkv + (size_t)(b * Sq) * (3 * Dm) + Dm + h * HDn + lk * 8;
  const bf16* vbase = vt + ((size_t)bh * HDn + lr) * 1024 + lk * 8;

  f32x4 o[8] = {};
  float m = 0.f, lsum = 0.f;

  const int ntiles = (rm0 >> 5) + 1;
  for (int kt = 0; kt < ntiles; ++kt) {
    const bf16* kp0 = kbase + (size_t)(kt * 32 + lr) * (3 * Dm);
    const bf16* kp1 = kp0 + (size_t)16 * (3 * Dm);
    bf16x8 kf0[4], kf1[4];
#pragma unroll
    for (int ks = 0; ks < 4; ++ks) {
      kf0[ks] = *(const bf16x8*)(kp0 + ks * 32);
      kf1[ks] = *(const bf16x8*)(kp1 + ks * 32);
    }
    f32x4 s0 = {0.f, 0.f, 0.f, 0.f}, s1 = {0.f, 0.f, 0.f, 0.f};
#pragma unroll
    for (int ks = 0; ks < 4; ++ks) {
      s0 = __builtin_amdgcn_mfma_f32_16x16x32_bf16(kf0[ks], qf[ks], s0, 0, 0, 0);
      s1 = __builtin_amdgcn_mfma_f32_16x16x32_bf16(kf1[ks], qf[ks], s1, 0, 0, 0);
    }
    if (kt == ntiles - 1) {
      const int kb = kt * 32 + lk * 4;
      const int r = rm0 + lr;
#pragma unroll
      for (int j = 0; j < 4; ++j) {
        if (kb + j > r)      s0[j] = -1e30f;
        if (kb + 16 + j > r) s1[j] = -1e30f;
      }
    }
    float tmax = fmaxf(fmaxf(fmaxf(s0[0], s0[1]), fmaxf(s0[2], s0[3])),
                       fmaxf(fmaxf(s1[0], s1[1]), fmaxf(s1[2], s1[3])));
    tmax = fmaxf(tmax, __shfl_xor(tmax, 16));
    tmax = fmaxf(tmax, __shfl_xor(tmax, 32));
    if (__builtin_expect(__any(tmax > m + 8.f), 0)) {
      const float mnew = fmaxf(m, tmax);
      const float alpha = __expf(m - mnew);
      m = mnew;
      lsum *= alpha;
      float aq[4];
#pragma unroll
      for (int j = 0; j < 4; ++j) aq[j] = __shfl(alpha, lk * 4 + j);
#pragma unroll
      for (int nt = 0; nt < 8; ++nt)
#pragma unroll
        for (int j = 0; j < 4; ++j) o[nt][j] *= aq[j];
    }
    float rs = 0.f;
    union { bf16x8 v; uint32_t uu[4]; } pk;
#pragma unroll
    for (int j = 0; j < 4; ++j) {
      const float p0 = __expf(s0[j] - m);
      const float p1 = __expf(s1[j] - m);
      rs += p0 + p1;
      pk.v[j] = (bf16)p0;
      pk.v[4 + j] = (bf16)p1;
    }
    rs += __shfl_xor(rs, 16);
    rs += __shfl_xor(rs, 32);
    lsum += rs;
    const int sA = lr + 16 * ((2 * lk) & 3);
    const int sB = lr + 16 * ((2 * lk + 1) & 3);
    const bool hi2 = ((lk >> 1) & 1) != 0;
    const uint32_t A0 = (uint32_t)__shfl((int)pk.uu[0], sA);
    const uint32_t A1 = (uint32_t)__shfl((int)pk.uu[1], sA);
    const uint32_t A2 = (uint32_t)__shfl((int)pk.uu[2], sA);
    const uint32_t A3 = (uint32_t)__shfl((int)pk.uu[3], sA);
    const uint32_t B0 = (uint32_t)__shfl((int)pk.uu[0], sB);
    const uint32_t B1 = (uint32_t)__shfl((int)pk.uu[1], sB);
    const uint32_t B2 = (uint32_t)__shfl((int)pk.uu[2], sB);
    const uint32_t B3 = (uint32_t)__shfl((int)pk.uu[3], sB);
    union { bf16x8 v; uint32_t uu[4]; } pa;
    pa.uu[0] = hi2 ? A2 : A0;
    pa.uu[1] = hi2 ? A3 : A1;
    pa.uu[2] = hi2 ? B2 : B0;
    pa.uu[3] = hi2 ? B3 : B1;
#pragma unroll
    for (int nt = 0; nt < 8; ++nt) {
      bf16x8 vf = *(const bf16x8*)(vbase + (size_t)nt * 16 * 1024 + kt * 32);
      o[nt] = __builtin_amdgcn_mfma_f32_16x16x32_bf16(pa.v, vf, o[nt], 0, 0, 0);
    }
  }
  const float rinv = 1.f / lsum;
  float rq[4];
#pragma unroll
  for (int j = 0; j < 4; ++j) rq[j] = __shfl(rinv, lk * 4 + j);
  bf16* ob = attnout + (size_t)(b * Sq + q0) * Dm + h * HDn;
#pragma unroll
  for (int nt = 0; nt < 8; ++nt)
#pragma unroll
    for (int j = 0; j < 4; ++j)
      ob[(size_t)(lk * 4 + j) * Dm + nt * 16 + lr] = (bf16)(o[nt][j] * rq[j]);
}

// ---------------- host launcher ----------------
extern "C" void kernel_launch(void* const* d_in, const int* in_sizes, int n_in,
                              void* d_out, int out_size, void* d_ws, size_t ws_size,
                              hipStream_t stream) {
  const float* x    = (const float*)d_in[0];
  const float* wqkv = (const float*)d_in[1];
  const float* wo   = (const float*)d_in[2];
  const float* w1   = (const float*)d_in[3];
  const float* b1   = (const float*)d_in[4];
  const float* w2   = (const float*)d_in[5];
  const float* b2   = (const float*)d_in[6];
  const float* g1   = (const float*)d_in[7];
  const float* be1  = (const float*)d_in[8];
  const float* g2   = (const float*)d_in[9];
  const float* be2  = (const float*)d_in[10];
  float* out = (float*)d_out;
  char* ws = (char*)d_ws;

  const size_t OFF_WQKVT = 0;                         // [6144][2048] bf16
  const size_t OFF_WOT   = OFF_WQKVT + 25165824;      // [2048][2048] bf16
  const size_t OFF_W1T   = OFF_WOT   + 8388608;       // [8192][2048] bf16
  const size_t OFF_W2T   = OFF_W1T   + 33554432;      // [2048][8192] bf16
  const size_t OFF_H     = OFF_W2T   + 33554432;      // [4096][2048] bf16
  const size_t OFF_QKV   = OFF_H     + 16777216;      // [4096][6144] bf16
  const size_t OFF_VT    = OFF_QKV   + 50331648;      // [32][128][1024] bf16
  const size_t OFF_ATT   = OFF_VT    + 16777216;      // [4096][2048] bf16
  const size_t OFF_X1    = OFF_ATT   + 16777216;      // [4096][2048] f32
  const size_t OFF_G     = OFF_QKV;                   // gelu buf reuses qkv+vt

  bf16* wqkvT = (bf16*)(ws + OFF_WQKVT);
  bf16* woT   = (bf16*)(ws + OFF_WOT);
  bf16* w1T   = (bf16*)(ws + OFF_W1T);
  bf16* w2T   = (bf16*)(ws + OFF_W2T);
  bf16* hbuf  = (bf16*)(ws + OFF_H);
  bf16* qkvb  = (bf16*)(ws + OFF_QKV);
  bf16* vtb   = (bf16*)(ws + OFF_VT);
  bf16* attb  = (bf16*)(ws + OFF_ATT);
  float* x1b  = (float*)(ws + OFF_X1);
  bf16* gbuf  = (bf16*)(ws + OFF_G);

  // weight convert+transpose to [N][K] bf16
  cvtT_kernel<<<dim3(192, 64), dim3(32, 8), 0, stream>>>(wqkv, wqkvT, 2048, 6144);
  cvtT_kernel<<<dim3(64, 64),  dim3(32, 8), 0, stream>>>(wo,   woT,   2048, 2048);
  cvtT_kernel<<<dim3(256, 64), dim3(32, 8), 0, stream>>>(w1,   w1T,   2048, 8192);
  cvtT_kernel<<<dim3(64, 256), dim3(32, 8), 0, stream>>>(w2,   w2T,   8192, 2048);

  // attention block
  ln_kernel<<<4096, 256, 0, stream>>>(x, g1, be1, hbuf);
  gemm8p<256, 0><<<dim3(16, 24), 512, 0, stream>>>(hbuf, wqkvT, qkvb, nullptr, nullptr, 4096, 6144, 2048);
  vtx_kernel<<<dim3(32, 4, 32), dim3(32, 8), 0, stream>>>(qkvb, vtb);
  attn_kernel<<<dim3(32, 32), 256, 0, stream>>>(qkvb, vtb, attb);
  gemm8p<128, 1><<<dim3(16, 16), 512, 0, stream>>>(attb, woT, x1b, nullptr, x, 4096, 2048, 2048);

  // MLP block
  ln_kernel<<<4096, 256, 0, stream>>>(x1b, g2, be2, hbuf);
  gemm8p<256, 2><<<dim3(16, 32), 512, 0, stream>>>(hbuf, w1T, gbuf, b1, nullptr, 4096, 8192, 2048);
  gemm8p<128, 3><<<dim3(16, 16), 512, 0, stream>>>(gbuf, w2T, out, b2, x1b, 4096, 2048, 8192);

  (void)in_sizes; (void)n_in; (void)out_size; (void)ws_size;
}

// Round 5
// 870.709 us; speedup vs baseline: 1.3151x; 1.0299x over previous
//
#include <hip/hip_runtime.h>
#include <hip/hip_bf16.h>
#include <cstdint>
#include <cstddef>

typedef __bf16 bf16;
typedef __attribute__((ext_vector_type(8))) __bf16 bf16x8;
typedef __attribute__((ext_vector_type(4))) float f32x4;

static constexpr int Dm = 2048;   // model dim
static constexpr int Sq = 2048;   // seq len
static constexpr int HDn = 128;   // head dim

#define BARX() asm volatile("s_barrier" ::: "memory")
#define WAITV2() asm volatile("s_waitcnt vmcnt(2)" ::: "memory")
#define WAITV0() asm volatile("s_waitcnt vmcnt(0)" ::: "memory")

// ---------------- async global->LDS (16B per lane) ----------------
__device__ __forceinline__ void gload_lds16(const void* gp, void* lp) {
  __builtin_amdgcn_global_load_lds(
      (__attribute__((address_space(1))) void*)(void*)gp,
      (__attribute__((address_space(3))) void*)lp,
      16, 0, 0);
}

// exact-to-1.5e-7 GELU via A&S 7.1.26 erf (1 __expf + ~12 fma, no branches)
__device__ __forceinline__ float gelu_fast(float x) {
  const float z = fabsf(x) * 0.7071067811865475f;
  const float t = 1.f / (1.f + 0.3275911f * z);
  const float poly = t * (0.254829592f +
                     t * (-0.284496736f +
                     t * (1.421413741f +
                     t * (-1.453152027f +
                     t * 1.061405429f))));
  float erf = 1.f - poly * __expf(-z * z);
  erf = copysignf(erf, x);
  return 0.5f * x * (1.f + erf);
}

// ---------------- LayerNorm: fp32 in -> bf16 out ----------------
__global__ __launch_bounds__(256) void ln_kernel(const float* __restrict__ x,
                                                 const float* __restrict__ g,
                                                 const float* __restrict__ be,
                                                 bf16* __restrict__ out) {
  const int row = blockIdx.x;
  const int t = threadIdx.x;
  const float* xr = x + (size_t)row * Dm;
  f32x4 a = *(const f32x4*)(xr + t * 8);
  f32x4 b = *(const f32x4*)(xr + t * 8 + 4);
  float s = 0.f, ss = 0.f;
#pragma unroll
  for (int i = 0; i < 4; i++) { s += a[i] + b[i]; ss += a[i]*a[i] + b[i]*b[i]; }
#pragma unroll
  for (int off = 32; off > 0; off >>= 1) { s += __shfl_xor(s, off); ss += __shfl_xor(ss, off); }
  __shared__ float ls[4], lss[4];
  if ((t & 63) == 0) { ls[t >> 6] = s; lss[t >> 6] = ss; }
  __syncthreads();
  s = ls[0] + ls[1] + ls[2] + ls[3];
  ss = lss[0] + lss[1] + lss[2] + lss[3];
  const float mean = s * (1.f / Dm);
  const float rstd = rsqrtf(ss * (1.f / Dm) - mean * mean + 1e-5f);
  f32x4 g0 = *(const f32x4*)(g + t * 8);
  f32x4 g1 = *(const f32x4*)(g + t * 8 + 4);
  f32x4 b0 = *(const f32x4*)(be + t * 8);
  f32x4 b1 = *(const f32x4*)(be + t * 8 + 4);
  bf16x8 o;
#pragma unroll
  for (int i = 0; i < 4; i++) {
    o[i]     = (bf16)((a[i] - mean) * rstd * g0[i] + b0[i]);
    o[i + 4] = (bf16)((b[i] - mean) * rstd * g1[i] + b1[i]);
  }
  *(bf16x8*)(out + (size_t)row * Dm + t * 8) = o;
}

// ------------- transpose + fp32->bf16 convert: out[c][r] = in[r][c] -------------
__global__ void cvtT_kernel(const float* __restrict__ in, bf16* __restrict__ out,
                            int R, int C) {
  __shared__ float tile[32][33];
  const int c0 = blockIdx.x * 32, r0 = blockIdx.y * 32;
  const int tx = threadIdx.x, ty = threadIdx.y;
#pragma unroll
  for (int i = 0; i < 4; i++)
    tile[ty + i * 8][tx] = in[(size_t)(r0 + ty + i * 8) * C + c0 + tx];
  __syncthreads();
#pragma unroll
  for (int i = 0; i < 4; i++)
    out[(size_t)(c0 + ty + i * 8) * R + r0 + tx] = (bf16)tile[tx][ty + i * 8];
}

// ------------- extract V^T per (b,h), keys s<1024 only: vt[bh][d][s] -------------
__global__ void vtx_kernel(const bf16* __restrict__ qkv, bf16* __restrict__ vt) {
  __shared__ bf16 tile[32][33];
  const int s0 = blockIdx.x * 32;   // 0..1023
  const int d0 = blockIdx.y * 32;
  const int bh = blockIdx.z;
  const int b = bh >> 4, h = bh & 15;
  const int tx = threadIdx.x, ty = threadIdx.y;
#pragma unroll
  for (int i = 0; i < 4; i++)
    tile[ty + i * 8][tx] =
        qkv[(size_t)(b * Sq + s0 + ty + i * 8) * (3 * Dm) + 2 * Dm + h * HDn + d0 + tx];
  __syncthreads();
#pragma unroll
  for (int i = 0; i < 4; i++)
    vt[((size_t)bh * HDn + d0 + ty + i * 8) * 1024 + s0 + tx] = tile[tx][ty + i * 8];
}

// =====================================================================
// 8-phase 256-tile GEMM: C[M,N] = A[M,K](bf16) @ BT[N,K](bf16)
// BM=256, BN=256 or 128, BK=64, 512 threads (8 waves, 2x4).
// Double-buffered LDS, XOR bank swizzle (both sides, rule #21),
// counted vmcnt published wait->barrier->read, setprio around MFMA.
// Block->tile mapping: 32-consecutive-slot regions pinned to one XCD
// (id%8 round-robin), each covering a compact 4m x 8n tile region
// so the per-XCD same-k working set (~256KB) fits L2.
// EPI 0: store bf16; 1: +resid, fp32; 2: +bias, GELU, bf16; 3: +bias+resid, fp32
// =====================================================================
template <int BN, int EPI>
__global__ __launch_bounds__(512, 2) void gemm8p(const bf16* __restrict__ A,
                                                 const bf16* __restrict__ BT,
                                                 void* __restrict__ Cout,
                                                 const float* __restrict__ bias,
                                                 const float* __restrict__ resid,
                                                 int M, int N, int K) {
  constexpr int NI  = BN / 64;   // n-frags per wave (4 or 2); also # B chunks
  constexpr int NI2 = NI / 2;    // per-quadrant n-frags (2 or 1)
  constexpr int BSTR = BN * 128; // per-buffer B bytes
  __shared__ alignas(16) char smem[65536 + 2 * BSTR];
  char* const As_ = smem;
  char* const Bs_ = smem + 65536;

  const int t = threadIdx.x;
  const int l = t & 63;
  const int lr = l & 15, lk = l >> 4;
  const int wv = t >> 6, wr = wv >> 2, wc = wv & 3;

  // ---- region mapping (bijective; gx%4==0, gy%8==0 for all our grids) ----
  const int gx = gridDim.x;
  const int nwg = gx * gridDim.y;
  const int id = blockIdx.y * gx + blockIdx.x;
  const int full = nwg & ~255;         // ids in complete 256-block rounds
  int region, w;
  if (id < full) {                     // XCD-pinned: ids {xcd + 8k}, 32 slots
    const int xcd = id & 7, k = id >> 3;
    region = (k >> 5) * 8 + xcd;
    w = k & 31;
  } else {                             // tail: consecutive ids, unpinned
    const int tid = id - full;
    region = (full >> 5) + (tid >> 5);
    w = tid & 31;
  }
  const int Rx = gx >> 2;              // regions along m (4 m-tiles each)
  const int rm = region % Rx, rn = region / Rx;
  const int m0 = (rm * 4 + (w & 3)) * 256;
  const int n0 = (rn * 8 + (w >> 2)) * BN;

  // read-side lane bases: 16B-slot within row = (4b + (lk^(lr&3))), data slot
  // = addr_slot ^ (lr&7); koff pair selects K-subtile 0 then 1 for all lanes.
  const int swz = 16 * (lk ^ (lr & 3));
  const int b2 = (lr >> 2) & 1;
  const int k0off = 64 * b2;
  const int k1off = 64 - 64 * b2;
  char* const Ard = As_ + wr * 16384 + lr * 128 + swz;
  char* const Brd = Bs_ + (BN == 256 ? ((wc >> 1) * 16384 + (wc & 1) * 8192)
                                     : wc * 4096) + lr * 128 + swz;

  // stage-side: thread t stages 16B; source col pre-permuted (rule #21)
  const int trow = t >> 3;                       // 0..63
  const int scol = 8 * ((t & 7) ^ (trow & 7));   // bf16 col within 64-wide K-tile
  const bf16* const Asrc = A + (size_t)(m0 + trow) * K + scol;
  const bf16* const Bsrc = BT + (size_t)(n0 + trow) * K + scol;
  char* const Adst = As_ + t * 16;
  char* const Bdst = Bs_ + t * 16;

  f32x4 acc[8][NI];
#pragma unroll
  for (int i = 0; i < 8; ++i)
#pragma unroll
    for (int j = 0; j < NI; ++j) acc[i][j] = (f32x4){0.f, 0.f, 0.f, 0.f};

  const int nt = K >> 6;

  // prologue: stage tile 0 into buf 0, drain, publish
#pragma unroll
  for (int ch = 0; ch < 4; ++ch)
    gload_lds16(Asrc + (size_t)ch * 64 * K, Adst + ch * 8192);
#pragma unroll
  for (int ch = 0; ch < NI; ++ch)
    gload_lds16(Bsrc + (size_t)ch * 64 * K, Bdst + ch * 8192);
  WAITV0();
  BARX();

  int buf = 0;
  for (int kt = 0; kt < nt; ++kt, buf ^= 1) {
    const int nb = buf ^ 1;
    const bool pf = (kt + 1) < nt;
    const size_t kg = (size_t)(kt + 1) * 64;
    char* const Ard_b  = Ard + buf * 32768;
    char* const Brd_b  = Brd + buf * BSTR;
    char* const Adst_b = Adst + nb * 32768;
    char* const Bdst_b = Bdst + nb * BSTR;
    bf16x8 a0[4][2], a1[4][2], b0[NI2][2], b1[NI2][2];

    // ---------- q0: read aLo+bLo, stage {A0,A2}, MFMA lo x lo ----------
#pragma unroll
    for (int mi = 0; mi < 4; ++mi) {
      a0[mi][0] = *(const bf16x8*)(Ard_b + mi * 2048 + k0off);
      a0[mi][1] = *(const bf16x8*)(Ard_b + mi * 2048 + k1off);
    }
#pragma unroll
    for (int ni = 0; ni < NI2; ++ni) {
      b0[ni][0] = *(const bf16x8*)(Brd_b + ni * 2048 + k0off);
      b0[ni][1] = *(const bf16x8*)(Brd_b + ni * 2048 + k1off);
    }
    if (pf) {
      gload_lds16(Asrc + kg, Adst_b);
      gload_lds16(Asrc + (size_t)128 * K + kg, Adst_b + 2 * 8192);
    }
    BARX();
    __builtin_amdgcn_s_setprio(1);
#pragma unroll
    for (int mi = 0; mi < 4; ++mi)
#pragma unroll
      for (int ni = 0; ni < NI2; ++ni) {
        acc[mi][ni] = __builtin_amdgcn_mfma_f32_16x16x32_bf16(a0[mi][0], b0[ni][0], acc[mi][ni], 0, 0, 0);
        acc[mi][ni] = __builtin_amdgcn_mfma_f32_16x16x32_bf16(a0[mi][1], b0[ni][1], acc[mi][ni], 0, 0, 0);
      }
    __builtin_amdgcn_s_setprio(0);
    // publish prev tile's {A1,A3} (retire all but the 2 loads just issued)
    if (pf) { WAITV2(); } else { WAITV0(); }
    BARX();

    // ---------- q1: read aHi, stage {B0,B1}, MFMA hi x lo ----------
#pragma unroll
    for (int mi = 0; mi < 4; ++mi) {
      a1[mi][0] = *(const bf16x8*)(Ard_b + (4 + mi) * 2048 + k0off);
      a1[mi][1] = *(const bf16x8*)(Ard_b + (4 + mi) * 2048 + k1off);
    }
    if (pf) {
      gload_lds16(Bsrc + kg, Bdst_b);
      gload_lds16(Bsrc + (size_t)64 * K + kg, Bdst_b + 8192);
    }
    BARX();
    __builtin_amdgcn_s_setprio(1);
#pragma unroll
    for (int mi = 0; mi < 4; ++mi)
#pragma unroll
      for (int ni = 0; ni < NI2; ++ni) {
        acc[4 + mi][ni] = __builtin_amdgcn_mfma_f32_16x16x32_bf16(a1[mi][0], b0[ni][0], acc[4 + mi][ni], 0, 0, 0);
        acc[4 + mi][ni] = __builtin_amdgcn_mfma_f32_16x16x32_bf16(a1[mi][1], b0[ni][1], acc[4 + mi][ni], 0, 0, 0);
      }
    __builtin_amdgcn_s_setprio(0);
    BARX();

    // ---------- q2: read bHi, stage {B2,B3}|{A1,A3}, MFMA lo x hi ----------
#pragma unroll
    for (int ni = 0; ni < NI2; ++ni) {
      b1[ni][0] = *(const bf16x8*)(Brd_b + (NI2 + ni) * 2048 + k0off);
      b1[ni][1] = *(const bf16x8*)(Brd_b + (NI2 + ni) * 2048 + k1off);
    }
    if (pf) {
      if (BN == 256) {
        gload_lds16(Bsrc + (size_t)128 * K + kg, Bdst_b + 2 * 8192);
        gload_lds16(Bsrc + (size_t)192 * K + kg, Bdst_b + 3 * 8192);
      } else {
        gload_lds16(Asrc + (size_t)64 * K + kg, Adst_b + 8192);
        gload_lds16(Asrc + (size_t)192 * K + kg, Adst_b + 3 * 8192);
      }
    }
    BARX();
    __builtin_amdgcn_s_setprio(1);
#pragma unroll
    for (int mi = 0; mi < 4; ++mi)
#pragma unroll
      for (int ni = 0; ni < NI2; ++ni) {
        acc[mi][NI2 + ni] = __builtin_amdgcn_mfma_f32_16x16x32_bf16(a0[mi][0], b1[ni][0], acc[mi][NI2 + ni], 0, 0, 0);
        acc[mi][NI2 + ni] = __builtin_amdgcn_mfma_f32_16x16x32_bf16(a0[mi][1], b1[ni][1], acc[mi][NI2 + ni], 0, 0, 0);
      }
    __builtin_amdgcn_s_setprio(0);
    BARX();

    // ---------- q3: stage {A1,A3} (BN=256), MFMA hi x hi ----------
    if (pf && BN == 256) {
      gload_lds16(Asrc + (size_t)64 * K + kg, Adst_b + 8192);
      gload_lds16(Asrc + (size_t)192 * K + kg, Adst_b + 3 * 8192);
    }
    BARX();
    __builtin_amdgcn_s_setprio(1);
#pragma unroll
    for (int mi = 0; mi < 4; ++mi)
#pragma unroll
      for (int ni = 0; ni < NI2; ++ni) {
        acc[4 + mi][NI2 + ni] = __builtin_amdgcn_mfma_f32_16x16x32_bf16(a1[mi][0], b1[ni][0], acc[4 + mi][NI2 + ni], 0, 0, 0);
        acc[4 + mi][NI2 + ni] = __builtin_amdgcn_mfma_f32_16x16x32_bf16(a1[mi][1], b1[ni][1], acc[4 + mi][NI2 + ni], 0, 0, 0);
      }
    __builtin_amdgcn_s_setprio(0);
    // publish this tile's {A0,A2,B*} for next q0 (keep newest 2 = {A1,A3})
    WAITV2();
    BARX();
  }

  // ---------------- epilogue ----------------
  const int rb = m0 + wr * 128 + lk * 4;
  const int cb = n0 + wc * (BN / 4) + lr;
#pragma unroll
  for (int mi = 0; mi < 8; ++mi) {
#pragma unroll
    for (int ni = 0; ni < NI; ++ni) {
#pragma unroll
      for (int j = 0; j < 4; ++j) {
        const int row = rb + mi * 16 + j;
        const int col = cb + ni * 16;
        float v = acc[mi][ni][j];
        if constexpr (EPI == 2 || EPI == 3) v += bias[col];
        if constexpr (EPI == 2) v = gelu_fast(v);
        if constexpr (EPI == 1 || EPI == 3) v += resid[(size_t)row * N + col];
        if constexpr (EPI == 0 || EPI == 2)
          ((bf16*)Cout)[(size_t)row * N + col] = (bf16)v;
        else
          ((float*)Cout)[(size_t)row * N + col] = v;
      }
    }
  }
}

// ---------------- flash attention, chunk mask: key j allowed iff j <= q%1024 ----------------
__global__ __launch_bounds__(256) void attn_kernel(const bf16* __restrict__ qkv,
                                                   const bf16* __restrict__ vt,
                                                   bf16* __restrict__ attnout) {
  const int t = threadIdx.x;
  const int wv = t >> 6, l = t & 63;
  const int lr = l & 15, lk = l >> 4;
  const int bh = blockIdx.y, b = bh >> 4, h = bh & 15;
  const int pp = blockIdx.x * 2 + (wv >> 1);
  const int c = pp >> 5, pb = pp & 31;
  const int u = (wv & 1) ? (63 - pb) : pb;   // query tile index within chunk (16 q each)
  const int q0 = c * 1024 + u * 16;
  const int rm0 = u * 16;                    // q%1024 of first query
  const float scale = 0.08838834764831845f;  // 1/sqrt(128)

  const bf16* qptr = qkv + (size_t)(b * Sq + q0 + lr) * (3 * Dm) + h * HDn + lk * 8;
  bf16x8 qf[4];
#pragma unroll
  for (int ks = 0; ks < 4; ++ks) {
    bf16x8 r = *(const bf16x8*)(qptr + ks * 32);
#pragma unroll
    for (int i = 0; i < 8; ++i) r[i] = (bf16)((float)r[i] * scale);
    qf[ks] = r;
  }

  const bf16* kbase = qkv + (size_t)(b * Sq) * (3 * Dm) + Dm + h * HDn + lk * 8;
  const bf16* vbase = vt + ((size_t)bh * HDn + lr) * 1024 + lk * 8;

  f32x4 o[8] = {};
  float m = 0.f, lsum = 0.f;

  const int ntiles = (rm0 >> 5) + 1;
  for (int kt = 0; kt < ntiles; ++kt) {
    const bf16* kp0 = kbase + (size_t)(kt * 32 + lr) * (3 * Dm);
    const bf16* kp1 = kp0 + (size_t)16 * (3 * Dm);
    bf16x8 kf0[4], kf1[4];
#pragma unroll
    for (int ks = 0; ks < 4; ++ks) {
      kf0[ks] = *(const bf16x8*)(kp0 + ks * 32);
      kf1[ks] = *(const bf16x8*)(kp1 + ks * 32);
    }
    f32x4 s0 = {0.f, 0.f, 0.f, 0.f}, s1 = {0.f, 0.f, 0.f, 0.f};
#pragma unroll
    for (int ks = 0; ks < 4; ++ks) {
      s0 = __builtin_amdgcn_mfma_f32_16x16x32_bf16(kf0[ks], qf[ks], s0, 0, 0, 0);
      s1 = __builtin_amdgcn_mfma_f32_16x16x32_bf16(kf1[ks], qf[ks], s1, 0, 0, 0);
    }
    if (kt == ntiles - 1) {
      const int kb = kt * 32 + lk * 4;
      const int r = rm0 + lr;
#pragma unroll
      for (int j = 0; j < 4; ++j) {
        if (kb + j > r)      s0[j] = -1e30f;
        if (kb + 16 + j > r) s1[j] = -1e30f;
      }
    }
    float tmax = fmaxf(fmaxf(fmaxf(s0[0], s0[1]), fmaxf(s0[2], s0[3])),
                       fmaxf(fmaxf(s1[0], s1[1]), fmaxf(s1[2], s1[3])));
    tmax = fmaxf(tmax, __shfl_xor(tmax, 16));
    tmax = fmaxf(tmax, __shfl_xor(tmax, 32));
    if (__builtin_expect(__any(tmax > m + 8.f), 0)) {
      const float mnew = fmaxf(m, tmax);
      const float alpha = __expf(m - mnew);
      m = mnew;
      lsum *= alpha;
      float aq[4];
#pragma unroll
      for (int j = 0; j < 4; ++j) aq[j] = __shfl(alpha, lk * 4 + j);
#pragma unroll
      for (int nt = 0; nt < 8; ++nt)
#pragma unroll
        for (int j = 0; j < 4; ++j) o[nt][j] *= aq[j];
    }
    float rs = 0.f;
    union { bf16x8 v; uint32_t uu[4]; } pk;
#pragma unroll
    for (int j = 0; j < 4; ++j) {
      const float p0 = __expf(s0[j] - m);
      const float p1 = __expf(s1[j] - m);
      rs += p0 + p1;
      pk.v[j] = (bf16)p0;
      pk.v[4 + j] = (bf16)p1;
    }
    rs += __shfl_xor(rs, 16);
    rs += __shfl_xor(rs, 32);
    lsum += rs;
    const int sA = lr + 16 * ((2 * lk) & 3);
    const int sB = lr + 16 * ((2 * lk + 1) & 3);
    const bool hi2 = ((lk >> 1) & 1) != 0;
    const uint32_t A0 = (uint32_t)__shfl((int)pk.uu[0], sA);
    const uint32_t A1 = (uint32_t)__shfl((int)pk.uu[1], sA);
    const uint32_t A2 = (uint32_t)__shfl((int)pk.uu[2], sA);
    const uint32_t A3 = (uint32_t)__shfl((int)pk.uu[3], sA);
    const uint32_t B0 = (uint32_t)__shfl((int)pk.uu[0], sB);
    const uint32_t B1 = (uint32_t)__shfl((int)pk.uu[1], sB);
    const uint32_t B2 = (uint32_t)__shfl((int)pk.uu[2], sB);
    const uint32_t B3 = (uint32_t)__shfl((int)pk.uu[3], sB);
    union { bf16x8 v; uint32_t uu[4]; } pa;
    pa.uu[0] = hi2 ? A2 : A0;
    pa.uu[1] = hi2 ? A3 : A1;
    pa.uu[2] = hi2 ? B2 : B0;
    pa.uu[3] = hi2 ? B3 : B1;
#pragma unroll
    for (int nt = 0; nt < 8; ++nt) {
      bf16x8 vf = *(const bf16x8*)(vbase + (size_t)nt * 16 * 1024 + kt * 32);
      o[nt] = __builtin_amdgcn_mfma_f32_16x16x32_bf16(pa.v, vf, o[nt], 0, 0, 0);
    }
  }
  const float rinv = 1.f / lsum;
  float rq[4];
#pragma unroll
  for (int j = 0; j < 4; ++j) rq[j] = __shfl(rinv, lk * 4 + j);
  bf16* ob = attnout + (size_t)(b * Sq + q0) * Dm + h * HDn;
#pragma unroll
  for (int nt = 0; nt < 8; ++nt)
#pragma unroll
    for (int j = 0; j < 4; ++j)
      ob[(size_t)(lk * 4 + j) * Dm + nt * 16 + lr] = (bf16)(o[nt][j] * rq[j]);
}

// ---------------- host launcher ----------------
extern "C" void kernel_launch(void* const* d_in, const int* in_sizes, int n_in,
                              void* d_out, int out_size, void* d_ws, size_t ws_size,
                              hipStream_t stream) {
  const float* x    = (const float*)d_in[0];
  const float* wqkv = (const float*)d_in[1];
  const float* wo   = (const float*)d_in[2];
  const float* w1   = (const float*)d_in[3];
  const float* b1   = (const float*)d_in[4];
  const float* w2   = (const float*)d_in[5];
  const float* b2   = (const float*)d_in[6];
  const float* g1   = (const float*)d_in[7];
  const float* be1  = (const float*)d_in[8];
  const float* g2   = (const float*)d_in[9];
  const float* be2  = (const float*)d_in[10];
  float* out = (float*)d_out;
  char* ws = (char*)d_ws;

  const size_t OFF_WQKVT = 0;                         // [6144][2048] bf16
  const size_t OFF_WOT   = OFF_WQKVT + 25165824;      // [2048][2048] bf16
  const size_t OFF_W1T   = OFF_WOT   + 8388608;       // [8192][2048] bf16
  const size_t OFF_W2T   = OFF_W1T   + 33554432;      // [2048][8192] bf16
  const size_t OFF_H     = OFF_W2T   + 33554432;      // [4096][2048] bf16
  const size_t OFF_QKV   = OFF_H     + 16777216;      // [4096][6144] bf16
  const size_t OFF_VT    = OFF_QKV   + 50331648;      // [32][128][1024] bf16
  const size_t OFF_ATT   = OFF_VT    + 16777216;      // [4096][2048] bf16
  const size_t OFF_X1    = OFF_ATT   + 16777216;      // [4096][2048] f32
  const size_t OFF_G     = OFF_QKV;                   // gelu buf reuses qkv+vt

  bf16* wqkvT = (bf16*)(ws + OFF_WQKVT);
  bf16* woT   = (bf16*)(ws + OFF_WOT);
  bf16* w1T   = (bf16*)(ws + OFF_W1T);
  bf16* w2T   = (bf16*)(ws + OFF_W2T);
  bf16* hbuf  = (bf16*)(ws + OFF_H);
  bf16* qkvb  = (bf16*)(ws + OFF_QKV);
  bf16* vtb   = (bf16*)(ws + OFF_VT);
  bf16* attb  = (bf16*)(ws + OFF_ATT);
  float* x1b  = (float*)(ws + OFF_X1);
  bf16* gbuf  = (bf16*)(ws + OFF_G);

  // weight convert+transpose to [N][K] bf16
  cvtT_kernel<<<dim3(192, 64), dim3(32, 8), 0, stream>>>(wqkv, wqkvT, 2048, 6144);
  cvtT_kernel<<<dim3(64, 64),  dim3(32, 8), 0, stream>>>(wo,   woT,   2048, 2048);
  cvtT_kernel<<<dim3(256, 64), dim3(32, 8), 0, stream>>>(w1,   w1T,   2048, 8192);
  cvtT_kernel<<<dim3(64, 256), dim3(32, 8), 0, stream>>>(w2,   w2T,   8192, 2048);

  // attention block
  ln_kernel<<<4096, 256, 0, stream>>>(x, g1, be1, hbuf);
  gemm8p<256, 0><<<dim3(16, 24), 512, 0, stream>>>(hbuf, wqkvT, qkvb, nullptr, nullptr, 4096, 6144, 2048);
  vtx_kernel<<<dim3(32, 4, 32), dim3(32, 8), 0, stream>>>(qkvb, vtb);
  attn_kernel<<<dim3(32, 32), 256, 0, stream>>>(qkvb, vtb, attb);
  gemm8p<128, 1><<<dim3(16, 16), 512, 0, stream>>>(attb, woT, x1b, nullptr, x, 4096, 2048, 2048);

  // MLP block
  ln_kernel<<<4096, 256, 0, stream>>>(x1b, g2, be2, hbuf);
  gemm8p<256, 2><<<dim3(16, 32), 512, 0, stream>>>(hbuf, w1T, gbuf, b1, nullptr, 4096, 8192, 2048);
  gemm8p<128, 3><<<dim3(16, 16), 512, 0, stream>>>(gbuf, w2T, out, b2, x1b, 4096, 2048, 8192);

  (void)in_sizes; (void)n_in; (void)out_size; (void)ws_size;
}

// Round 6
// 845.612 us; speedup vs baseline: 1.3541x; 1.0297x over previous
//
#include <hip/hip_runtime.h>
#include <hip/hip_bf16.h>
#include <cstdint>
#include <cstddef>

typedef __bf16 bf16;
typedef __attribute__((ext_vector_type(8))) __bf16 bf16x8;
typedef __attribute__((ext_vector_type(4))) float f32x4;

static constexpr int Dm = 2048;   // model dim
static constexpr int Sq = 2048;   // seq len
static constexpr int HDn = 128;   // head dim

#define BARX() asm volatile("s_barrier" ::: "memory")
#define WAITVN(n) asm volatile("s_waitcnt vmcnt(" #n ")" ::: "memory")

// ---------------- async global->LDS (16B per lane) ----------------
__device__ __forceinline__ void gload_lds16(const void* gp, void* lp) {
  __builtin_amdgcn_global_load_lds(
      (__attribute__((address_space(1))) void*)(void*)gp,
      (__attribute__((address_space(3))) void*)lp,
      16, 0, 0);
}

// exact-to-1.5e-7 GELU via A&S 7.1.26 erf (1 __expf + ~12 fma, no branches)
__device__ __forceinline__ float gelu_fast(float x) {
  const float z = fabsf(x) * 0.7071067811865475f;
  const float t = 1.f / (1.f + 0.3275911f * z);
  const float poly = t * (0.254829592f +
                     t * (-0.284496736f +
                     t * (1.421413741f +
                     t * (-1.453152027f +
                     t * 1.061405429f))));
  float erf = 1.f - poly * __expf(-z * z);
  erf = copysignf(erf, x);
  return 0.5f * x * (1.f + erf);
}

// ---------------- LayerNorm: fp32 in -> bf16 out ----------------
__global__ __launch_bounds__(256) void ln_kernel(const float* __restrict__ x,
                                                 const float* __restrict__ g,
                                                 const float* __restrict__ be,
                                                 bf16* __restrict__ out) {
  const int row = blockIdx.x;
  const int t = threadIdx.x;
  const float* xr = x + (size_t)row * Dm;
  f32x4 a = *(const f32x4*)(xr + t * 8);
  f32x4 b = *(const f32x4*)(xr + t * 8 + 4);
  float s = 0.f, ss = 0.f;
#pragma unroll
  for (int i = 0; i < 4; i++) { s += a[i] + b[i]; ss += a[i]*a[i] + b[i]*b[i]; }
#pragma unroll
  for (int off = 32; off > 0; off >>= 1) { s += __shfl_xor(s, off); ss += __shfl_xor(ss, off); }
  __shared__ float ls[4], lss[4];
  if ((t & 63) == 0) { ls[t >> 6] = s; lss[t >> 6] = ss; }
  __syncthreads();
  s = ls[0] + ls[1] + ls[2] + ls[3];
  ss = lss[0] + lss[1] + lss[2] + lss[3];
  const float mean = s * (1.f / Dm);
  const float rstd = rsqrtf(ss * (1.f / Dm) - mean * mean + 1e-5f);
  f32x4 g0 = *(const f32x4*)(g + t * 8);
  f32x4 g1 = *(const f32x4*)(g + t * 8 + 4);
  f32x4 b0 = *(const f32x4*)(be + t * 8);
  f32x4 b1 = *(const f32x4*)(be + t * 8 + 4);
  bf16x8 o;
#pragma unroll
  for (int i = 0; i < 4; i++) {
    o[i]     = (bf16)((a[i] - mean) * rstd * g0[i] + b0[i]);
    o[i + 4] = (bf16)((b[i] - mean) * rstd * g1[i] + b1[i]);
  }
  *(bf16x8*)(out + (size_t)row * Dm + t * 8) = o;
}

// ------------- transpose + fp32->bf16 convert: out[c][r] = in[r][c] -------------
__global__ void cvtT_kernel(const float* __restrict__ in, bf16* __restrict__ out,
                            int R, int C) {
  __shared__ float tile[32][33];
  const int c0 = blockIdx.x * 32, r0 = blockIdx.y * 32;
  const int tx = threadIdx.x, ty = threadIdx.y;
#pragma unroll
  for (int i = 0; i < 4; i++)
    tile[ty + i * 8][tx] = in[(size_t)(r0 + ty + i * 8) * C + c0 + tx];
  __syncthreads();
#pragma unroll
  for (int i = 0; i < 4; i++)
    out[(size_t)(c0 + ty + i * 8) * R + r0 + tx] = (bf16)tile[tx][ty + i * 8];
}

// ------------- extract V^T per (b,h), keys s<1024 only: vt[bh][d][s] -------------
__global__ void vtx_kernel(const bf16* __restrict__ qkv, bf16* __restrict__ vt) {
  __shared__ bf16 tile[32][33];
  const int s0 = blockIdx.x * 32;   // 0..1023
  const int d0 = blockIdx.y * 32;
  const int bh = blockIdx.z;
  const int b = bh >> 4, h = bh & 15;
  const int tx = threadIdx.x, ty = threadIdx.y;
#pragma unroll
  for (int i = 0; i < 4; i++)
    tile[ty + i * 8][tx] =
        qkv[(size_t)(b * Sq + s0 + ty + i * 8) * (3 * Dm) + 2 * Dm + h * HDn + d0 + tx];
  __syncthreads();
#pragma unroll
  for (int i = 0; i < 4; i++)
    vt[((size_t)bh * HDn + d0 + ty + i * 8) * 1024 + s0 + tx] = tile[tx][ty + i * 8];
}

// =====================================================================
// 8-phase 256-tile GEMM: C[M,N] = A[M,K](bf16) @ BT[N,K](bf16)
// BM=256, BN=256 or 128, BK=64, 512 threads (8 waves, 2x4).
// Double-buffered LDS, XOR bank swizzle (both sides), setprio on MFMA.
// Staging front-loaded (q0:4, q1:2, q2:2) so issue->consume distance is
// >=2.2 phases for {A0,A2,B*} (published q3-end vmcnt(2)) and 3.2 phases
// for {A1,A3} (published next-q1-end vmcnt(6)/(4)); never vmcnt(0) midloop.
// EPI 0: store bf16; 1: +resid, fp32; 2: +bias, GELU, bf16; 3: +bias+resid, fp32
// =====================================================================
template <int BN, int EPI>
__global__ __launch_bounds__(512, 2) void gemm8p(const bf16* __restrict__ A,
                                                 const bf16* __restrict__ BT,
                                                 void* __restrict__ Cout,
                                                 const float* __restrict__ bias,
                                                 const float* __restrict__ resid,
                                                 int M, int N, int K) {
  constexpr int NI  = BN / 64;   // n-frags per wave (4 or 2); also # B chunks
  constexpr int NI2 = NI / 2;    // per-quadrant n-frags (2 or 1)
  constexpr int BSTR = BN * 128; // per-buffer B bytes
  __shared__ alignas(16) char smem[65536 + 2 * BSTR];
  char* const As_ = smem;
  char* const Bs_ = smem + 65536;

  const int t = threadIdx.x;
  const int l = t & 63;
  const int lr = l & 15, lk = l >> 4;
  const int wv = t >> 6, wr = wv >> 2, wc = wv & 3;

  // ---- region mapping (bijective; gx%4==0 for all our grids) ----
  const int gx = gridDim.x;
  const int nwg = gx * gridDim.y;
  const int id = blockIdx.y * gx + blockIdx.x;
  const int full = nwg & ~255;         // ids in complete 256-block rounds
  int region, w;
  if (id < full) {                     // XCD-pinned: ids {xcd + 8k}, 32 slots
    const int xcd = id & 7, k = id >> 3;
    region = (k >> 5) * 8 + xcd;
    w = k & 31;
  } else {                             // tail: consecutive ids, unpinned
    const int tid = id - full;
    region = (full >> 5) + (tid >> 5);
    w = tid & 31;
  }
  const int Rx = gx >> 2;              // regions along m (4 m-tiles each)
  const int rm = region % Rx, rn = region / Rx;
  const int m0 = (rm * 4 + (w & 3)) * 256;
  const int n0 = (rn * 8 + (w >> 2)) * BN;

  // read-side lane bases
  const int swz = 16 * (lk ^ (lr & 3));
  const int b2 = (lr >> 2) & 1;
  const int k0off = 64 * b2;
  const int k1off = 64 - 64 * b2;
  char* const Ard = As_ + wr * 16384 + lr * 128 + swz;
  char* const Brd = Bs_ + (BN == 256 ? ((wc >> 1) * 16384 + (wc & 1) * 8192)
                                     : wc * 4096) + lr * 128 + swz;

  // stage-side: thread t stages 16B; source col pre-permuted (rule #21)
  const int trow = t >> 3;                       // 0..63
  const int scol = 8 * ((t & 7) ^ (trow & 7));   // bf16 col within 64-wide K-tile
  const bf16* const Asrc = A + (size_t)(m0 + trow) * K + scol;
  const bf16* const Bsrc = BT + (size_t)(n0 + trow) * K + scol;
  char* const Adst = As_ + t * 16;
  char* const Bdst = Bs_ + t * 16;

  f32x4 acc[8][NI];
#pragma unroll
  for (int i = 0; i < 8; ++i)
#pragma unroll
    for (int j = 0; j < NI; ++j) acc[i][j] = (f32x4){0.f, 0.f, 0.f, 0.f};

  const int nt = K >> 6;

  // prologue: stage tile 0 into buf 0, drain, publish
#pragma unroll
  for (int ch = 0; ch < 4; ++ch)
    gload_lds16(Asrc + (size_t)ch * 64 * K, Adst + ch * 8192);
#pragma unroll
  for (int ch = 0; ch < NI; ++ch)
    gload_lds16(Bsrc + (size_t)ch * 64 * K, Bdst + ch * 8192);
  WAITVN(0);
  BARX();

  int buf = 0;
  for (int kt = 0; kt < nt; ++kt, buf ^= 1) {
    const int nb = buf ^ 1;
    const bool pf = (kt + 1) < nt;
    const size_t kg = (size_t)(kt + 1) * 64;
    char* const Ard_b  = Ard + buf * 32768;
    char* const Brd_b  = Brd + buf * BSTR;
    char* const Adst_b = Adst + nb * 32768;
    char* const Bdst_b = Bdst + nb * BSTR;
    bf16x8 a0[4][2], a1[4][2], b0[NI2][2], b1[NI2][2];

    // ---- q0: read aLo+bLo, stage {A0,A2,B0,B1}, MFMA lo x lo ----
#pragma unroll
    for (int mi = 0; mi < 4; ++mi) {
      a0[mi][0] = *(const bf16x8*)(Ard_b + mi * 2048 + k0off);
      a0[mi][1] = *(const bf16x8*)(Ard_b + mi * 2048 + k1off);
    }
#pragma unroll
    for (int ni = 0; ni < NI2; ++ni) {
      b0[ni][0] = *(const bf16x8*)(Brd_b + ni * 2048 + k0off);
      b0[ni][1] = *(const bf16x8*)(Brd_b + ni * 2048 + k1off);
    }
    if (pf) {
      gload_lds16(Asrc + kg, Adst_b);                          // A0
      gload_lds16(Asrc + (size_t)128 * K + kg, Adst_b + 2 * 8192);  // A2
      gload_lds16(Bsrc + kg, Bdst_b);                          // B0
      gload_lds16(Bsrc + (size_t)64 * K + kg, Bdst_b + 8192);  // B1
    }
    BARX();
    __builtin_amdgcn_s_setprio(1);
#pragma unroll
    for (int mi = 0; mi < 4; ++mi)
#pragma unroll
      for (int ni = 0; ni < NI2; ++ni) {
        acc[mi][ni] = __builtin_amdgcn_mfma_f32_16x16x32_bf16(a0[mi][0], b0[ni][0], acc[mi][ni], 0, 0, 0);
        acc[mi][ni] = __builtin_amdgcn_mfma_f32_16x16x32_bf16(a0[mi][1], b0[ni][1], acc[mi][ni], 0, 0, 0);
      }
    __builtin_amdgcn_s_setprio(0);
    BARX();

    // ---- q1: read bHi, stage {B2,B3} (BN=256), MFMA lo x hi ----
#pragma unroll
    for (int ni = 0; ni < NI2; ++ni) {
      b1[ni][0] = *(const bf16x8*)(Brd_b + (NI2 + ni) * 2048 + k0off);
      b1[ni][1] = *(const bf16x8*)(Brd_b + (NI2 + ni) * 2048 + k1off);
    }
    if (pf && BN == 256) {
      gload_lds16(Bsrc + (size_t)128 * K + kg, Bdst_b + 2 * 8192);  // B2
      gload_lds16(Bsrc + (size_t)192 * K + kg, Bdst_b + 3 * 8192);  // B3
    }
    BARX();
    __builtin_amdgcn_s_setprio(1);
#pragma unroll
    for (int mi = 0; mi < 4; ++mi)
#pragma unroll
      for (int ni = 0; ni < NI2; ++ni) {
        acc[mi][NI2 + ni] = __builtin_amdgcn_mfma_f32_16x16x32_bf16(a0[mi][0], b1[ni][0], acc[mi][NI2 + ni], 0, 0, 0);
        acc[mi][NI2 + ni] = __builtin_amdgcn_mfma_f32_16x16x32_bf16(a0[mi][1], b1[ni][1], acc[mi][NI2 + ni], 0, 0, 0);
      }
    __builtin_amdgcn_s_setprio(0);
    // publish prev tile's {A1,A3} before q2 reads aHi
    if (pf) {
      if constexpr (BN == 256) { WAITVN(6); } else { WAITVN(4); }
    } else {
      WAITVN(0);
    }
    BARX();

    // ---- q2: read aHi, stage {A1,A3}, MFMA hi x lo ----
#pragma unroll
    for (int mi = 0; mi < 4; ++mi) {
      a1[mi][0] = *(const bf16x8*)(Ard_b + (4 + mi) * 2048 + k0off);
      a1[mi][1] = *(const bf16x8*)(Ard_b + (4 + mi) * 2048 + k1off);
    }
    if (pf) {
      gload_lds16(Asrc + (size_t)64 * K + kg, Adst_b + 8192);       // A1
      gload_lds16(Asrc + (size_t)192 * K + kg, Adst_b + 3 * 8192);  // A3
    }
    BARX();
    __builtin_amdgcn_s_setprio(1);
#pragma unroll
    for (int mi = 0; mi < 4; ++mi)
#pragma unroll
      for (int ni = 0; ni < NI2; ++ni) {
        acc[4 + mi][ni] = __builtin_amdgcn_mfma_f32_16x16x32_bf16(a1[mi][0], b0[ni][0], acc[4 + mi][ni], 0, 0, 0);
        acc[4 + mi][ni] = __builtin_amdgcn_mfma_f32_16x16x32_bf16(a1[mi][1], b0[ni][1], acc[4 + mi][ni], 0, 0, 0);
      }
    __builtin_amdgcn_s_setprio(0);
    BARX();

    // ---- q3: MFMA hi x hi, publish {A0,A2,B*} for next q0 ----
    __builtin_amdgcn_s_setprio(1);
#pragma unroll
    for (int mi = 0; mi < 4; ++mi)
#pragma unroll
      for (int ni = 0; ni < NI2; ++ni) {
        acc[4 + mi][NI2 + ni] = __builtin_amdgcn_mfma_f32_16x16x32_bf16(a1[mi][0], b1[ni][0], acc[4 + mi][NI2 + ni], 0, 0, 0);
        acc[4 + mi][NI2 + ni] = __builtin_amdgcn_mfma_f32_16x16x32_bf16(a1[mi][1], b1[ni][1], acc[4 + mi][NI2 + ni], 0, 0, 0);
      }
    __builtin_amdgcn_s_setprio(0);
    if (pf) { WAITVN(2); }   // keep only {A1,A3} in flight
    BARX();
  }

  // ---------------- epilogue ----------------
  const int rb = m0 + wr * 128 + lk * 4;
  const int cb = n0 + wc * (BN / 4) + lr;
#pragma unroll
  for (int mi = 0; mi < 8; ++mi) {
#pragma unroll
    for (int ni = 0; ni < NI; ++ni) {
#pragma unroll
      for (int j = 0; j < 4; ++j) {
        const int row = rb + mi * 16 + j;
        const int col = cb + ni * 16;
        float v = acc[mi][ni][j];
        if constexpr (EPI == 2 || EPI == 3) v += bias[col];
        if constexpr (EPI == 2) v = gelu_fast(v);
        if constexpr (EPI == 1 || EPI == 3) v += resid[(size_t)row * N + col];
        if constexpr (EPI == 0 || EPI == 2)
          ((bf16*)Cout)[(size_t)row * N + col] = (bf16)v;
        else
          ((float*)Cout)[(size_t)row * N + col] = v;
      }
    }
  }
}

// ---------------- flash attention, chunk mask: key j allowed iff j <= q%1024 ----------------
__global__ __launch_bounds__(256) void attn_kernel(const bf16* __restrict__ qkv,
                                                   const bf16* __restrict__ vt,
                                                   bf16* __restrict__ attnout) {
  const int t = threadIdx.x;
  const int wv = t >> 6, l = t & 63;
  const int lr = l & 15, lk = l >> 4;
  const int bh = blockIdx.y, b = bh >> 4, h = bh & 15;
  const int pp = blockIdx.x * 2 + (wv >> 1);
  const int c = pp >> 5, pb = pp & 31;
  const int u = (wv & 1) ? (63 - pb) : pb;   // query tile index within chunk (16 q each)
  const int q0 = c * 1024 + u * 16;
  const int rm0 = u * 16;                    // q%1024 of first query
  const float scale = 0.08838834764831845f;  // 1/sqrt(128)

  const bf16* qptr = qkv + (size_t)(b * Sq + q0 + lr) * (3 * Dm) + h * HDn + lk * 8;
  bf16x8 qf[4];
#pragma unroll
  for (int ks = 0; ks < 4; ++ks) {
    bf16x8 r = *(const bf16x8*)(qptr + ks * 32);
#pragma unroll
    for (int i = 0; i < 8; ++i) r[i] = (bf16)((float)r[i] * scale);
    qf[ks] = r;
  }

  const bf16* kbase = qkv + (size_t)(b * Sq) * (3 * Dm) + Dm + h * HDn + lk * 8;
  const bf16* vbase = vt + ((size_t)bh * HDn + lr) * 1024 + lk * 8;

  f32x4 o[8] = {};
  float m = 0.f, lsum = 0.f;

  const int ntiles = (rm0 >> 5) + 1;
  for (int kt = 0; kt < ntiles; ++kt) {
    const bf16* kp0 = kbase + (size_t)(kt * 32 + lr) * (3 * Dm);
    const bf16* kp1 = kp0 + (size_t)16 * (3 * Dm);
    bf16x8 kf0[4], kf1[4];
#pragma unroll
    for (int ks = 0; ks < 4; ++ks) {
      kf0[ks] = *(const bf16x8*)(kp0 + ks * 32);
      kf1[ks] = *(const bf16x8*)(kp1 + ks * 32);
    }
    f32x4 s0 = {0.f, 0.f, 0.f, 0.f}, s1 = {0.f, 0.f, 0.f, 0.f};
#pragma unroll
    for (int ks = 0; ks < 4; ++ks) {
      s0 = __builtin_amdgcn_mfma_f32_16x16x32_bf16(kf0[ks], qf[ks], s0, 0, 0, 0);
      s1 = __builtin_amdgcn_mfma_f32_16x16x32_bf16(kf1[ks], qf[ks], s1, 0, 0, 0);
    }
    if (kt == ntiles - 1) {
      const int kb = kt * 32 + lk * 4;
      const int r = rm0 + lr;
#pragma unroll
      for (int j = 0; j < 4; ++j) {
        if (kb + j > r)      s0[j] = -1e30f;
        if (kb + 16 + j > r) s1[j] = -1e30f;
      }
    }
    float tmax = fmaxf(fmaxf(fmaxf(s0[0], s0[1]), fmaxf(s0[2], s0[3])),
                       fmaxf(fmaxf(s1[0], s1[1]), fmaxf(s1[2], s1[3])));
    tmax = fmaxf(tmax, __shfl_xor(tmax, 16));
    tmax = fmaxf(tmax, __shfl_xor(tmax, 32));
    if (__builtin_expect(__any(tmax > m + 8.f), 0)) {
      const float mnew = fmaxf(m, tmax);
      const float alpha = __expf(m - mnew);
      m = mnew;
      lsum *= alpha;
      float aq[4];
#pragma unroll
      for (int j = 0; j < 4; ++j) aq[j] = __shfl(alpha, lk * 4 + j);
#pragma unroll
      for (int nt = 0; nt < 8; ++nt)
#pragma unroll
        for (int j = 0; j < 4; ++j) o[nt][j] *= aq[j];
    }
    float rs = 0.f;
    union { bf16x8 v; uint32_t uu[4]; } pk;
#pragma unroll
    for (int j = 0; j < 4; ++j) {
      const float p0 = __expf(s0[j] - m);
      const float p1 = __expf(s1[j] - m);
      rs += p0 + p1;
      pk.v[j] = (bf16)p0;
      pk.v[4 + j] = (bf16)p1;
    }
    rs += __shfl_xor(rs, 16);
    rs += __shfl_xor(rs, 32);
    lsum += rs;
    const int sA = lr + 16 * ((2 * lk) & 3);
    const int sB = lr + 16 * ((2 * lk + 1) & 3);
    const bool hi2 = ((lk >> 1) & 1) != 0;
    const uint32_t A0 = (uint32_t)__shfl((int)pk.uu[0], sA);
    const uint32_t A1 = (uint32_t)__shfl((int)pk.uu[1], sA);
    const uint32_t A2 = (uint32_t)__shfl((int)pk.uu[2], sA);
    const uint32_t A3 = (uint32_t)__shfl((int)pk.uu[3], sA);
    const uint32_t B0 = (uint32_t)__shfl((int)pk.uu[0], sB);
    const uint32_t B1 = (uint32_t)__shfl((int)pk.uu[1], sB);
    const uint32_t B2 = (uint32_t)__shfl((int)pk.uu[2], sB);
    const uint32_t B3 = (uint32_t)__shfl((int)pk.uu[3], sB);
    union { bf16x8 v; uint32_t uu[4]; } pa;
    pa.uu[0] = hi2 ? A2 : A0;
    pa.uu[1] = hi2 ? A3 : A1;
    pa.uu[2] = hi2 ? B2 : B0;
    pa.uu[3] = hi2 ? B3 : B1;
#pragma unroll
    for (int nt = 0; nt < 8; ++nt) {
      bf16x8 vf = *(const bf16x8*)(vbase + (size_t)nt * 16 * 1024 + kt * 32);
      o[nt] = __builtin_amdgcn_mfma_f32_16x16x32_bf16(pa.v, vf, o[nt], 0, 0, 0);
    }
  }
  const float rinv = 1.f / lsum;
  float rq[4];
#pragma unroll
  for (int j = 0; j < 4; ++j) rq[j] = __shfl(rinv, lk * 4 + j);
  bf16* ob = attnout + (size_t)(b * Sq + q0) * Dm + h * HDn;
#pragma unroll
  for (int nt = 0; nt < 8; ++nt)
#pragma unroll
    for (int j = 0; j < 4; ++j)
      ob[(size_t)(lk * 4 + j) * Dm + nt * 16 + lr] = (bf16)(o[nt][j] * rq[j]);
}

// ---------------- host launcher ----------------
extern "C" void kernel_launch(void* const* d_in, const int* in_sizes, int n_in,
                              void* d_out, int out_size, void* d_ws, size_t ws_size,
                              hipStream_t stream) {
  const float* x    = (const float*)d_in[0];
  const float* wqkv = (const float*)d_in[1];
  const float* wo   = (const float*)d_in[2];
  const float* w1   = (const float*)d_in[3];
  const float* b1   = (const float*)d_in[4];
  const float* w2   = (const float*)d_in[5];
  const float* b2   = (const float*)d_in[6];
  const float* g1   = (const float*)d_in[7];
  const float* be1  = (const float*)d_in[8];
  const float* g2   = (const float*)d_in[9];
  const float* be2  = (const float*)d_in[10];
  float* out = (float*)d_out;
  char* ws = (char*)d_ws;

  const size_t OFF_WQKVT = 0;                         // [6144][2048] bf16
  const size_t OFF_WOT   = OFF_WQKVT + 25165824;      // [2048][2048] bf16
  const size_t OFF_W1T   = OFF_WOT   + 8388608;       // [8192][2048] bf16
  const size_t OFF_W2T   = OFF_W1T   + 33554432;      // [2048][8192] bf16
  const size_t OFF_H     = OFF_W2T   + 33554432;      // [4096][2048] bf16
  const size_t OFF_QKV   = OFF_H     + 16777216;      // [4096][6144] bf16
  const size_t OFF_VT    = OFF_QKV   + 50331648;      // [32][128][1024] bf16
  const size_t OFF_ATT   = OFF_VT    + 16777216;      // [4096][2048] bf16
  const size_t OFF_X1    = OFF_ATT   + 16777216;      // [4096][2048] f32
  const size_t OFF_G     = OFF_QKV;                   // gelu buf reuses qkv+vt

  bf16* wqkvT = (bf16*)(ws + OFF_WQKVT);
  bf16* woT   = (bf16*)(ws + OFF_WOT);
  bf16* w1T   = (bf16*)(ws + OFF_W1T);
  bf16* w2T   = (bf16*)(ws + OFF_W2T);
  bf16* hbuf  = (bf16*)(ws + OFF_H);
  bf16* qkvb  = (bf16*)(ws + OFF_QKV);
  bf16* vtb   = (bf16*)(ws + OFF_VT);
  bf16* attb  = (bf16*)(ws + OFF_ATT);
  float* x1b  = (float*)(ws + OFF_X1);
  bf16* gbuf  = (bf16*)(ws + OFF_G);

  // weight convert+transpose to [N][K] bf16
  cvtT_kernel<<<dim3(192, 64), dim3(32, 8), 0, stream>>>(wqkv, wqkvT, 2048, 6144);
  cvtT_kernel<<<dim3(64, 64),  dim3(32, 8), 0, stream>>>(wo,   woT,   2048, 2048);
  cvtT_kernel<<<dim3(256, 64), dim3(32, 8), 0, stream>>>(w1,   w1T,   2048, 8192);
  cvtT_kernel<<<dim3(64, 256), dim3(32, 8), 0, stream>>>(w2,   w2T,   8192, 2048);

  // attention block
  ln_kernel<<<4096, 256, 0, stream>>>(x, g1, be1, hbuf);
  gemm8p<256, 0><<<dim3(16, 24), 512, 0, stream>>>(hbuf, wqkvT, qkvb, nullptr, nullptr, 4096, 6144, 2048);
  vtx_kernel<<<dim3(32, 4, 32), dim3(32, 8), 0, stream>>>(qkvb, vtb);
  attn_kernel<<<dim3(32, 32), 256, 0, stream>>>(qkvb, vtb, attb);
  gemm8p<128, 1><<<dim3(16, 16), 512, 0, stream>>>(attb, woT, x1b, nullptr, x, 4096, 2048, 2048);

  // MLP block
  ln_kernel<<<4096, 256, 0, stream>>>(x1b, g2, be2, hbuf);
  gemm8p<256, 2><<<dim3(16, 32), 512, 0, stream>>>(hbuf, w1T, gbuf, b1, nullptr, 4096, 8192, 2048);
  gemm8p<128, 3><<<dim3(16, 16), 512, 0, stream>>>(gbuf, w2T, out, b2, x1b, 4096, 2048, 8192);

  (void)in_sizes; (void)n_in; (void)out_size; (void)ws_size;
}